// Round 13
// baseline (485.458 us; speedup 1.0000x reference)
//
#include <hip/hip_runtime.h>
#include <math.h>

typedef _Float16 __attribute__((ext_vector_type(8))) half8_t;
typedef _Float16 __attribute__((ext_vector_type(4))) half4_t;
typedef _Float16 __attribute__((ext_vector_type(2))) half2_t;
typedef float    __attribute__((ext_vector_type(4))) float4_t;

// ---------------------------------------------------------------------------
// Kernel 1: fully-MFMA conv1 + conv2 + maxpool4 (block = 16x16 output tile).
// R12: hi-only activations. LDS 27.5 KB -> 5 blocks/CU.
// ---------------------------------------------------------------------------
#define POSP 336

__device__ __forceinline__ int c1idx(int slot, int pos) {
    return ((slot * POSP + pos) * 8) ^ (((pos >> 3) & 7) << 3);
}

__global__ __launch_bounds__(256, 5)
void k_conv12(const float* __restrict__ img, const float* __restrict__ b1,
              const _Float16* __restrict__ B1h, const _Float16* __restrict__ B1l,
              const _Float16* __restrict__ B2h, const _Float16* __restrict__ B2l,
              const float* __restrict__ b2,
              _Float16* __restrict__ P1h)
{
    __shared__ float simg[3 * 20 * 25];                    // input halo-2
    __shared__ __align__(16) _Float16 C1h[4 * POSP * 8];   // A, then conv1 out

    const int t  = threadIdx.x;
    const int bt = blockIdx.x;
    const int b  = blockIdx.y;
    const int ty = bt >> 3, tx = bt & 7;
    const int oy = ty * 16, ox = tx * 16;

    // ---- Phase A1: stage fp32 halo (bounds-checked ONCE, zero-padded) ----
    for (int i = t; i < 1500; i += 256) {
        const int ci = i / 500, r = i - ci * 500;
        const int yy = r / 25, xx = r - yy * 25;
        const int gy = oy - 2 + yy, gx = ox - 2 + xx;
        float v = 0.f;
        if ((unsigned)gy < 128u && (unsigned)gx < 128u)
            v = img[((b * 3 + ci) * 128 + gy) * 128 + gx];
        simg[i] = v;
    }
    __syncthreads();

    // ---- Phase A2: im2col simg -> C1h (hi only; compile-time tap offsets) --
    #pragma unroll
    for (int hf = 0; hf < 2; ++hf) {
        const int pos = hf * 256 + t;
        if (pos < POSP) {
            const bool val = pos < 324;
            int sb = 0;
            if (val) {
                const int py = pos / 18, px = pos - py * 18;
                sb = py * 25 + px;
            }
            #pragma unroll
            for (int s = 0; s < 4; ++s) {
                half8_t vh = {0,0,0,0,0,0,0,0};
                if (val) {
                    #pragma unroll
                    for (int j = 0; j < 8; ++j) {
                        const int k = s * 8 + j;
                        if (k < 27) {
                            const int ci = k / 9, tap = k - ci * 9;   // const
                            const int dy = tap / 3, dx = tap - dy * 3; // const
                            vh[j] = (_Float16)simg[sb + (ci * 20 + dy) * 25 + dx];
                        }
                    }
                }
                *(half8_t*)(&C1h[c1idx(s, pos)]) = vh;
            }
        }
    }
    __syncthreads();

    const int wv   = __builtin_amdgcn_readfirstlane(t >> 6);
    const int lane = t & 63;
    const int fr   = lane >> 4;
    const int ml   = lane & 15;

    // ---- Phase B: conv1 MFMA, transposed, 2-term: D[ch][pos] = w @ xh ----
    half8_t wAh[2], wAl[2];
    #pragma unroll
    for (int mt = 0; mt < 2; ++mt) {
        wAh[mt] = *(const half8_t*)(B1h + (mt * 64 + lane) * 8);
        wAl[mt] = *(const half8_t*)(B1l + (mt * 64 + lane) * 8);
    }
    float4_t acc1[6][2];
    #pragma unroll
    for (int q = 0; q < 6; ++q)
        #pragma unroll
        for (int mt = 0; mt < 2; ++mt)
            acc1[q][mt] = (float4_t){0.f, 0.f, 0.f, 0.f};

    #pragma unroll
    for (int q = 0; q < 6; ++q) {
        const int nt = wv + q * 4;
        if (nt < 21) {
            const int ri = c1idx(fr, nt * 16 + ml);
            const half8_t dh = *(const half8_t*)(&C1h[ri]);
            #pragma unroll
            for (int mt = 0; mt < 2; ++mt) {
                acc1[q][mt] = __builtin_amdgcn_mfma_f32_16x16x32_f16(wAh[mt], dh, acc1[q][mt], 0, 0, 0);
                acc1[q][mt] = __builtin_amdgcn_mfma_f32_16x16x32_f16(wAl[mt], dh, acc1[q][mt], 0, 0, 0);
            }
        }
    }
    __syncthreads();          // all A reads done; buffer reusable

    // ---- Phase C: epilogue -> overwrite C1h (hi only). ----
    const float4_t bA = *(const float4_t*)(b1 + fr * 4);
    const float4_t bB = *(const float4_t*)(b1 + 16 + fr * 4);
    #pragma unroll
    for (int q = 0; q < 6; ++q) {
        const int nt = wv + q * 4;
        if (nt < 21) {
            const int pos = nt * 16 + ml;
            if (pos < 324) {
                const int py = pos / 18, px = pos - py * 18;
                const int gy = oy + py - 1, gx = ox + px - 1;
                const bool ok = (unsigned)gy < 128u && (unsigned)gx < 128u;
                #pragma unroll
                for (int mt = 0; mt < 2; ++mt) {
                    const int slot = mt * 2 + (fr >> 1);
                    const int wi = c1idx(slot, pos) + (fr & 1) * 4;
                    const float4_t bb = mt ? bB : bA;
                    half4_t oh;
                    #pragma unroll
                    for (int r = 0; r < 4; ++r) {
                        const float v = ok ? fmaxf(acc1[q][mt][r] + bb[r], 0.f) : 0.f;
                        oh[r] = (_Float16)v;
                    }
                    *(half4_t*)(&C1h[wi]) = oh;
                }
            }
        }
    }
    __syncthreads();

    // ---- Phase D: conv2 implicit-GEMM 2-term, wave wv owns rows wv*4.. ----
    float4_t acc[4][2];
    #pragma unroll
    for (int i = 0; i < 4; ++i)
        #pragma unroll
        for (int nt = 0; nt < 2; ++nt)
            acc[i][nt] = (float4_t){0.f, 0.f, 0.f, 0.f};

    #pragma unroll 1
    for (int tap = 0; tap < 9; ++tap) {
        const int dy = tap / 3, dx = tap - dy * 3;
        half8_t bh[2], bl[2];
        #pragma unroll
        for (int nt = 0; nt < 2; ++nt) {
            const int bo = ((tap * 2 + nt) * 64 + lane) * 8;
            bh[nt] = *(const half8_t*)(B2h + bo);
            bl[nt] = *(const half8_t*)(B2l + bo);
        }
        half8_t ah[4];
        #pragma unroll
        for (int i = 0; i < 4; ++i) {
            const int pos = (wv * 4 + i + dy) * 18 + ml + dx;
            ah[i] = *(const half8_t*)(&C1h[c1idx(fr, pos)]);
        }
        #pragma unroll
        for (int nt = 0; nt < 2; ++nt)
            #pragma unroll
            for (int i = 0; i < 4; ++i)
                acc[i][nt] = __builtin_amdgcn_mfma_f32_16x16x32_f16(ah[i], bh[nt], acc[i][nt], 0, 0, 0);
        #pragma unroll
        for (int nt = 0; nt < 2; ++nt)
            #pragma unroll
            for (int i = 0; i < 4; ++i)
                acc[i][nt] = __builtin_amdgcn_mfma_f32_16x16x32_f16(ah[i], bl[nt], acc[i][nt], 0, 0, 0);
    }

    // ---- maxpool4 (thread-local) + bias + relu + hi store ----
    const int py = ty * 4 + wv;
    const int px = tx * 4 + fr;
    #pragma unroll
    for (int nt = 0; nt < 2; ++nt) {
        float m = -1e30f;
        #pragma unroll
        for (int i = 0; i < 4; ++i)
            #pragma unroll
            for (int r = 0; r < 4; ++r)
                m = fmaxf(m, acc[i][nt][r]);
        const int oc = nt * 16 + ml;
        const float v = fmaxf(m + b2[oc], 0.f);
        P1h[((b * 32 + py) * 32 + px) * 32 + oc] = (_Float16)v;
    }
}

// ---------------------------------------------------------------------------
// Weight repack: fp16 hi/lo MFMA-fragment packs for w2..w6 (+ w1, K padded
// 27->32). Frag order: Bh[((c*NT + ntg)*64 + lane)*8 + j], element B[k][n]:
//   n = ntg*16 + (lane&15), k = c*32 + (lane>>4)*8 + j.
// ---------------------------------------------------------------------------
__global__ void k_wrepackm(const float* __restrict__ w1, const float* __restrict__ w2,
                           const float* __restrict__ w3, const float* __restrict__ w4,
                           const float* __restrict__ w5, const float* __restrict__ w6,
                           _Float16* __restrict__ Bh, _Float16* __restrict__ Bl,
                           _Float16* __restrict__ B1h, _Float16* __restrict__ B1l)
{
    int idx = blockIdx.x * 256 + threadIdx.x;
    if (idx >= 285696) {
        const int i = idx - 285696;
        if (i >= 1024) return;
        const int ntg = i >> 9, rr = i & 511;
        const int lane = rr >> 3, j = rr & 7;
        const int k = (lane >> 4) * 8 + j;
        const int n = ntg * 16 + (lane & 15);
        const float v = (k < 27) ? w1[n * 27 + k] : 0.f;
        const _Float16 h = (_Float16)v;
        B1h[i] = h;
        B1l[i] = (_Float16)(v - (float)h);
        return;
    }
    const float* w; int CIN, COUT, off;
    if (idx < 9216)        { w = w2; CIN = 32;  COUT = 32;  off = 0; }
    else if (idx < 27648)  { idx -= 9216;   w = w3; CIN = 32;  COUT = 64;  off = 9216; }
    else if (idx < 64512)  { idx -= 27648;  w = w4; CIN = 64;  COUT = 64;  off = 27648; }
    else if (idx < 138240) { idx -= 64512;  w = w5; CIN = 64;  COUT = 128; off = 64512; }
    else                   { idx -= 138240; w = w6; CIN = 128; COUT = 128; off = 138240; }
    const int NT  = COUT / 16;
    const int c   = idx / (NT * 512);
    const int r   = idx - c * NT * 512;
    const int ntg = r >> 9;
    const int rr  = r & 511;
    const int lane = rr >> 3, j = rr & 7;
    const int k   = c * 32 + (lane >> 4) * 8 + j;
    const int tap = k / CIN, ci = k - tap * CIN;
    const int oc  = ntg * 16 + (lane & 15);
    const float v = w[(oc * CIN + ci) * 9 + tap];
    const _Float16 h = (_Float16)v;
    Bh[off + idx] = h;
    Bl[off + idx] = (_Float16)(v - (float)h);
}

// ---------------------------------------------------------------------------
// MFMA implicit-GEMM conv3x3, hi-only activations, 2-term split.
// BM=128, BN=64; 4 waves = 2 m-tiles x 4 n-tiles. BK=64 for CIN>=64.
// launch_bounds (256,3): R12's (256,4) capped VGPR at 128 -> pressure
// regression; 3 keeps >=3 blocks/CU with 168-reg headroom.
// POOL2 (conv4): fused 2x2 maxpool epilogue via Ash reuse -> writes P2
// directly (block covers 4 y-rows x 32 x x all 64 ch -> self-contained).
// OUTLO=true (conv6) emits hi/lo for the K=32768 FC1 accumulation.
// ---------------------------------------------------------------------------
template<int CIN, int COUT, int HW, bool OUTLO, int BK, bool POOL2>
__global__ __launch_bounds__(256, 3)
void k_mgemm(const _Float16* __restrict__ inh,
             const _Float16* __restrict__ Bh, const _Float16* __restrict__ Bl,
             const float* __restrict__ bias,
             _Float16* __restrict__ outh, _Float16* __restrict__ outl)
{
    constexpr int NCH = CIN * 9 / BK;
    constexpr int SUB = BK / 32;
    constexpr int NT  = COUT / 16;
    constexpr int LOG = (HW == 32) ? 5 : 4;
    constexpr int PS  = BK + ((BK == 64) ? 4 : 8);
    constexpr int NJ  = BK / 16;          // staging iterations
    constexpr int GPR = BK / 8;           // half8 groups per row
    __shared__ _Float16 Ash[128 * PS];

    const int t    = threadIdx.x;
    const int wv   = t >> 6;
    const int lane = t & 63;
    const int m0   = blockIdx.x * 128;
    const int nb   = blockIdx.y;

    int sm[NJ], sg[NJ], sb[NJ], sy[NJ], sx[NJ];
    #pragma unroll
    for (int j = 0; j < NJ; ++j) {
        const int q = t + 256 * j;
        sm[j] = q / GPR;
        sg[j] = q - sm[j] * GPR;
        const int m  = m0 + sm[j];
        const int yx = m & (HW * HW - 1);
        sb[j] = m >> (2 * LOG);
        sy[j] = yx >> LOG;
        sx[j] = yx & (HW - 1);
    }

    const int mt0 = wv * 2;
    const int fr  = lane >> 4;
    const int ml  = lane & 15;

    float4_t acc[2][4];
    #pragma unroll
    for (int mt = 0; mt < 2; ++mt)
        #pragma unroll
        for (int tn = 0; tn < 4; ++tn)
            acc[mt][tn] = (float4_t){0.f, 0.f, 0.f, 0.f};

    #pragma unroll 1
    for (int ch = 0; ch < NCH; ++ch) {
        const int kb  = ch * BK;
        const int tap = kb / CIN;
        const int c0  = kb - tap * CIN;
        const int dy  = tap / 3 - 1, dx = tap - (tap / 3) * 3 - 1;

        if (ch) __syncthreads();
        #pragma unroll
        for (int j = 0; j < NJ; ++j) {
            const int iy = sy[j] + dy, ix = sx[j] + dx;
            half8_t vh = {0, 0, 0, 0, 0, 0, 0, 0};
            if ((unsigned)iy < (unsigned)HW && (unsigned)ix < (unsigned)HW) {
                const int o = ((sb[j] * HW + iy) * HW + ix) * CIN + c0 + sg[j] * 8;
                vh = *(const half8_t*)(inh + o);
            }
            *(half8_t*)(&Ash[sm[j] * PS + sg[j] * 8]) = vh;
        }
        __syncthreads();

        #pragma unroll
        for (int ss = 0; ss < SUB; ++ss) {
            half8_t ah[2];
            #pragma unroll
            for (int mt = 0; mt < 2; ++mt) {
                const int mr = (mt0 + mt) * 16 + ml;
                ah[mt] = *(const half8_t*)(&Ash[mr * PS + ss * 32 + fr * 8]);
            }
            half8_t bh[4], bl[4];
            #pragma unroll
            for (int tn = 0; tn < 4; ++tn) {
                const int bo = (((ch * SUB + ss) * NT + nb * 4 + tn) * 64 + lane) * 8;
                bh[tn] = *(const half8_t*)(Bh + bo);
                bl[tn] = *(const half8_t*)(Bl + bo);
            }
            #pragma unroll
            for (int tn = 0; tn < 4; ++tn)
                #pragma unroll
                for (int mt = 0; mt < 2; ++mt)
                    acc[mt][tn] = __builtin_amdgcn_mfma_f32_16x16x32_f16(ah[mt], bh[tn], acc[mt][tn], 0, 0, 0);
            #pragma unroll
            for (int tn = 0; tn < 4; ++tn)
                #pragma unroll
                for (int mt = 0; mt < 2; ++mt)
                    acc[mt][tn] = __builtin_amdgcn_mfma_f32_16x16x32_f16(ah[mt], bl[tn], acc[mt][tn], 0, 0, 0);
        }
    }

    if (POOL2) {
        // ---- fused 2x2 pool epilogue (conv4): Ash reuse, PADW=68 ----
        __syncthreads();     // all frag reads done before Ash overwrite
        #pragma unroll
        for (int mt = 0; mt < 2; ++mt)
            #pragma unroll
            for (int tn = 0; tn < 4; ++tn) {
                const int oc = tn * 16 + ml;
                const float bv = bias[oc];
                #pragma unroll
                for (int r = 0; r < 4; ++r) {
                    const int ml_loc = (mt0 + mt) * 16 + fr * 4 + r;
                    const float v = fmaxf(acc[mt][tn][r] + bv, 0.f);
                    Ash[ml_loc * 68 + oc] = (_Float16)v;
                }
            }
        __syncthreads();
        const int bidx = m0 >> (2 * LOG);
        const int y0   = (m0 >> LOG) & (HW - 1);
        for (int q = t; q < 512; q += 256) {
            const int ocq = q & 15, xo = (q >> 4) & 15, yo = q >> 8;
            const int base = (yo * 64 + xo * 2) * 68 + ocq * 4;
            half4_t a0 = *(const half4_t*)(&Ash[base]);
            const half4_t a1 = *(const half4_t*)(&Ash[base + 68]);
            const half4_t a2 = *(const half4_t*)(&Ash[base + 32 * 68]);
            const half4_t a3 = *(const half4_t*)(&Ash[base + 33 * 68]);
            #pragma unroll
            for (int e = 0; e < 4; ++e) {
                _Float16 m = a0[e];
                m = (a1[e] > m) ? a1[e] : m;
                m = (a2[e] > m) ? a2[e] : m;
                m = (a3[e] > m) ? a3[e] : m;
                a0[e] = m;
            }
            const int ob = ((bidx * 16 + (y0 >> 1) + yo) * 16 + xo) * 64 + ocq * 4;
            *(half4_t*)(&outh[ob]) = a0;
        }
    } else {
        // epilogue: C/D frag col=lane&15, row=(lane>>4)*4+reg [guide m89/m91]
        #pragma unroll
        for (int mt = 0; mt < 2; ++mt)
            #pragma unroll
            for (int tn = 0; tn < 4; ++tn) {
                const int oc = nb * 64 + tn * 16 + ml;
                const float bv = bias[oc];
                #pragma unroll
                for (int r = 0; r < 4; ++r) {
                    const int m = m0 + (mt0 + mt) * 16 + fr * 4 + r;
                    const float v = fmaxf(acc[mt][tn][r] + bv, 0.f);
                    const _Float16 h = (_Float16)v;
                    outh[m * COUT + oc] = h;
                    if (OUTLO)
                        outl[m * COUT + oc] = (_Float16)(v - (float)h);
                }
            }
    }
}

// ---------------------------------------------------------------------------
// MFMA FC1: H1-partials = A[128 x 32768] @ wl1[32768 x 512], split-K.
// A from fp16 hi/lo A6 planes; W fp32 direct from wl1 (perm folded), hi/lo
// converted in-LDS. 3-term split = fp32-class. Partials fp32.
// ---------------------------------------------------------------------------
__global__ __launch_bounds__(256, 2)
void k_fc1m(const _Float16* __restrict__ A6h, const _Float16* __restrict__ A6l,
            const float* __restrict__ wl1, float* __restrict__ part)
{
    __shared__ __align__(16) _Float16 Ah[128 * 68];
    __shared__ __align__(16) _Float16 Al[128 * 68];
    __shared__ __align__(16) _Float16 Wh[64 * 68];
    __shared__ __align__(16) _Float16 Wl[64 * 68];

    const int t    = threadIdx.x;
    const int wv   = t >> 6;
    const int lane = t & 63;
    const int fr   = lane >> 4;
    const int ml   = lane & 15;
    const int n0   = blockIdx.x * 64;
    const int kc   = blockIdx.y;

    float4_t acc[2][4];
    #pragma unroll
    for (int mt = 0; mt < 2; ++mt)
        #pragma unroll
        for (int tn = 0; tn < 4; ++tn)
            acc[mt][tn] = (float4_t){0.f, 0.f, 0.f, 0.f};

    #pragma unroll 1
    for (int it = 0; it < 8; ++it) {
        const int kb = kc * 512 + it * 64;
        const int yx = kb >> 7;           // 64-k window never crosses yx
        const int c0 = kb & 127;

        if (it) __syncthreads();
        // stage A [128 b][64 k] hi/lo (coalesced 128B runs per b)
        #pragma unroll
        for (int q = 0; q < 4; ++q) {
            const int lin = q * 256 + t;
            const int bb = lin >> 3, g = lin & 7;
            const int src = (bb * 256 + yx) * 128 + c0 + g * 8;
            *(half8_t*)(&Ah[bb * 68 + g * 8]) = *(const half8_t*)(A6h + src);
            *(half8_t*)(&Al[bb * 68 + g * 8]) = *(const half8_t*)(A6l + src);
        }
        // stage W: wl1 row kref=(c0+kk)*256+yx, 64 n fp32 -> hi/lo [n][68]
        {
            const int kk = t >> 2;
            const float* wrow = wl1 + ((c0 + kk) * 256 + yx) * 512 + n0;
            #pragma unroll
            for (int q = 0; q < 4; ++q) {
                const int nq = (t & 3) + q * 4;
                const float4 v = *(const float4*)(wrow + nq * 4);
                #pragma unroll
                for (int e = 0; e < 4; ++e) {
                    const int n = nq * 4 + e;
                    const float w = (&v.x)[e];
                    const _Float16 h = (_Float16)w;
                    Wh[n * 68 + kk] = h;
                    Wl[n * 68 + kk] = (_Float16)(w - (float)h);
                }
            }
        }
        __syncthreads();

        #pragma unroll
        for (int ss = 0; ss < 2; ++ss) {
            half8_t ah[2], al[2];
            #pragma unroll
            for (int mt = 0; mt < 2; ++mt) {
                const int bb = (wv * 2 + mt) * 16 + ml;
                ah[mt] = *(const half8_t*)(&Ah[bb * 68 + ss * 32 + fr * 8]);
                al[mt] = *(const half8_t*)(&Al[bb * 68 + ss * 32 + fr * 8]);
            }
            half8_t bh[4], bl[4];
            #pragma unroll
            for (int tn = 0; tn < 4; ++tn) {
                const int nn = tn * 16 + ml;
                bh[tn] = *(const half8_t*)(&Wh[nn * 68 + ss * 32 + fr * 8]);
                bl[tn] = *(const half8_t*)(&Wl[nn * 68 + ss * 32 + fr * 8]);
            }
            #pragma unroll
            for (int tn = 0; tn < 4; ++tn)
                #pragma unroll
                for (int mt = 0; mt < 2; ++mt)
                    acc[mt][tn] = __builtin_amdgcn_mfma_f32_16x16x32_f16(ah[mt], bh[tn], acc[mt][tn], 0, 0, 0);
            #pragma unroll
            for (int tn = 0; tn < 4; ++tn)
                #pragma unroll
                for (int mt = 0; mt < 2; ++mt)
                    acc[mt][tn] = __builtin_amdgcn_mfma_f32_16x16x32_f16(al[mt], bh[tn], acc[mt][tn], 0, 0, 0);
            #pragma unroll
            for (int tn = 0; tn < 4; ++tn)
                #pragma unroll
                for (int mt = 0; mt < 2; ++mt)
                    acc[mt][tn] = __builtin_amdgcn_mfma_f32_16x16x32_f16(ah[mt], bl[tn], acc[mt][tn], 0, 0, 0);
        }
    }

    // partials (no bias/relu -- reduce applies them)
    const long pb = (long)kc * 65536;
    #pragma unroll
    for (int mt = 0; mt < 2; ++mt)
        #pragma unroll
        for (int tn = 0; tn < 4; ++tn) {
            const int nn = n0 + tn * 16 + ml;
            #pragma unroll
            for (int r = 0; r < 4; ++r) {
                const int m = (wv * 2 + mt) * 16 + fr * 4 + r;
                part[pb + m * 512 + nn] = acc[mt][tn][r];
            }
        }
}

// ---------------------------------------------------------------------------
// Split-K FC partial (fp32): A[128 x K] @ B[K x 512] -> part[ky][128][512]
// (FC2 only)
// ---------------------------------------------------------------------------
template<int LDA, int KCHUNK, int TN, bool PERM>
__global__ __launch_bounds__(256, 2)
void k_fc_partial(const float* __restrict__ A, const float* __restrict__ Bw,
                  float* __restrict__ part)
{
    constexpr int BN = 16 * TN;
    constexpr int SA = 140;
    constexpr int SB = (BN == 128) ? 140 : 68;
    __shared__ __align__(16) float As[32 * SA];
    __shared__ __align__(16) float Bs[32 * SB];
    const int t  = threadIdx.x;
    const int tm = t >> 4, tn = t & 15;
    const int n0 = blockIdx.x * BN;
    const int k0 = blockIdx.y * KCHUNK;

    float acc[8][TN];
    #pragma unroll
    for (int r = 0; r < 8; ++r)
        #pragma unroll
        for (int c = 0; c < TN; ++c) acc[r][c] = 0.f;

    #pragma unroll 1
    for (int ks = 0; ks < KCHUNK / 32; ++ks) {
        if (ks) __syncthreads();
        const int kb = k0 + ks * 32;
        for (int i = t; i < 4096; i += 256) {
            const int m = i >> 5, kk = i & 31;
            As[kk * SA + m + ((m >> 5) << 2)] = A[m * LDA + kb + kk];
        }
        for (int i = t; i < 32 * BN; i += 256) {
            const int kk = i / BN, n = i - kk * BN;
            const int krow = kb + kk;
            const int kref = PERM ? ((krow & 127) * 256 + (krow >> 7)) : krow;
            Bs[kk * SB + n + ((n >> 5) << 2)] = Bw[kref * 512 + n0 + n];
        }
        __syncthreads();
        #pragma unroll 2
        for (int kk = 0; kk < 32; ++kk) {
            const float* ap = &As[kk * SA + tm * 8 + ((tm >> 2) << 2)];
            const float* bp = &Bs[kk * SB + tn * TN + (((tn * TN) >> 5) << 2)];
            float a[8], bb[TN];
            #pragma unroll
            for (int q = 0; q < 8; q += 4) {
                const float4 v = *(const float4*)(ap + q);
                a[q] = v.x; a[q + 1] = v.y; a[q + 2] = v.z; a[q + 3] = v.w;
            }
            #pragma unroll
            for (int q = 0; q < TN; q += 4) {
                const float4 v = *(const float4*)(bp + q);
                bb[q] = v.x; bb[q + 1] = v.y; bb[q + 2] = v.z; bb[q + 3] = v.w;
            }
            #pragma unroll
            for (int r = 0; r < 8; ++r)
                #pragma unroll
                for (int c = 0; c < TN; ++c)
                    acc[r][c] = fmaf(a[r], bb[c], acc[r][c]);
        }
    }

    const long pb = (long)blockIdx.y * 65536;
    #pragma unroll
    for (int r = 0; r < 8; ++r)
        #pragma unroll
        for (int c = 0; c < TN; ++c)
            part[pb + (tm * 8 + r) * 512 + n0 + tn * TN + c] = acc[r][c];
}

template<int NS>
__global__ __launch_bounds__(256)
void k_fc_reduce(const float* __restrict__ part, const float* __restrict__ bias,
                 float* __restrict__ H)
{
    const int f = (blockIdx.x * 256 + threadIdx.x) * 4;
    const int m = f >> 9, n = f & 511;
    float s0 = 0.f, s1 = 0.f, s2 = 0.f, s3 = 0.f;
    #pragma unroll 4
    for (int q = 0; q < NS; ++q) {
        const float* p = &part[(q * 128 + m) * 512 + n];
        s0 += p[0]; s1 += p[1]; s2 += p[2]; s3 += p[3];
    }
    H[f]     = fmaxf(s0 + bias[n],     0.f);
    H[f + 1] = fmaxf(s1 + bias[n + 1], 0.f);
    H[f + 2] = fmaxf(s2 + bias[n + 2], 0.f);
    H[f + 3] = fmaxf(s3 + bias[n + 3], 0.f);
}

// ---------------------------------------------------------------------------
// Final: FC3 + sampling + patch gather
// ---------------------------------------------------------------------------
__device__ __forceinline__ float softplusf(float x) {
    return (x > 20.f) ? x : log1pf(expf(x));
}
__device__ __forceinline__ float sigmoidf_(float x) {
    return 1.f / (1.f + expf(-x));
}

__global__ __launch_bounds__(256)
void k_final(const float* __restrict__ H2, const float* __restrict__ wl3,
             const float* __restrict__ bl3, const float* __restrict__ noise,
             const float* __restrict__ img, float* __restrict__ outp)
{
    __shared__ float h2[512];
    __shared__ float red[144];
    __shared__ float prep[36];
    __shared__ int ptsh[12], ptsw[12];
    const int b = blockIdx.x, t = threadIdx.x;

    h2[t]       = H2[b * 512 + t];
    h2[t + 256] = H2[b * 512 + 256 + t];
    __syncthreads();

    if (t < 144) {
        const int n = t >> 2, q = t & 3;
        float s = 0.f;
        for (int k = q * 128; k < q * 128 + 128; ++k)
            s = fmaf(h2[k], wl3[k * 36 + n], s);
        red[t] = s;
    }
    __syncthreads();
    if (t < 36)
        prep[t] = red[t * 4] + red[t * 4 + 1] + red[t * 4 + 2] + red[t * 4 + 3] + bl3[t];
    __syncthreads();

    if (t < 12) {
        const float m0 = prep[t * 3], m1 = prep[t * 3 + 1], sv = prep[t * 3 + 2];
        const float sig = softplusf(sv + 2.0f) * 128.f + 1e-7f;
        const float n0 = noise[(b * 12 + t) * 2], n1 = noise[(b * 12 + t) * 2 + 1];
        const float sa0 = m0 + sig * n0;
        const float sa1 = m1 + sig * n1;
        int p0 = (int)rintf(sigmoidf_(sa0) * 111.f);
        int p1 = (int)rintf(sigmoidf_(sa1) * 111.f);
        p0 = min(max(p0, 0), 111);
        p1 = min(max(p1, 0), 111);
        const int RM = 1179648;
        outp[RM        + (b * 12 + t) * 2 + 0] = m0;
        outp[RM        + (b * 12 + t) * 2 + 1] = m1;
        outp[RM + 3072 + (b * 12 + t) * 2 + 0] = sig;
        outp[RM + 3072 + (b * 12 + t) * 2 + 1] = sig;
        outp[RM + 6144 + (b * 12 + t) * 2 + 0] = sa0;
        outp[RM + 6144 + (b * 12 + t) * 2 + 1] = sa1;
        ptsh[t] = p0;
        ptsw[t] = p1;
    }
    __syncthreads();

    for (int i = t; i < 9216; i += 256) {
        const int g  = i / 768, r = i - g * 768;
        const int c  = r >> 8, r2 = r & 255;
        const int y  = r2 >> 4, x = r2 & 15;
        outp[b * 9216 + i] = img[((b * 3 + c) * 128 + ptsh[g] + y) * 128 + (ptsw[g] + x)];
    }
}

// ---------------------------------------------------------------------------
extern "C" void kernel_launch(void* const* d_in, const int* in_sizes, int n_in,
                              void* d_out, int out_size, void* d_ws, size_t ws_size,
                              hipStream_t stream)
{
    const float* img  = (const float*)d_in[0];
    const float* nois = (const float*)d_in[1];
    const float* w1 = (const float*)d_in[2];  const float* b1 = (const float*)d_in[3];
    const float* w2 = (const float*)d_in[4];  const float* b2 = (const float*)d_in[5];
    const float* w3 = (const float*)d_in[6];  const float* b3 = (const float*)d_in[7];
    const float* w4 = (const float*)d_in[8];  const float* b4 = (const float*)d_in[9];
    const float* w5 = (const float*)d_in[10]; const float* b5 = (const float*)d_in[11];
    const float* w6 = (const float*)d_in[12]; const float* b6 = (const float*)d_in[13];
    const float* wl1 = (const float*)d_in[14]; const float* bl1 = (const float*)d_in[15];
    const float* wl2 = (const float*)d_in[16]; const float* bl2 = (const float*)d_in[17];
    const float* wl3 = (const float*)d_in[18]; const float* bl3 = (const float*)d_in[19];
    float* out = (float*)d_out;
    float* ws  = (float*)d_ws;

    // workspace (float units). Hi-only activations; A4 eliminated (fused pool).
    _Float16* P1h = (_Float16*)(ws);               // [128*32*32*32] ..2097152
    _Float16* A3h = (_Float16*)(ws + 2097152);     // [128*32*32*64] ..6291456
    _Float16* P2h = (_Float16*)(ws + 6291456);     // [128*16*16*64] ..7340032
    _Float16* A5h = (_Float16*)(ws);               // [128*16*16*128] (P1 dead)
    _Float16* A6h = (_Float16*)(ws + 2097152);     // [32768*128] (A3 dead)
    _Float16* A6l = (_Float16*)(ws + 4194304);     // ..6291456 (A3 dead)
    float* FP1 = ws + 12582912;                    // [64][128][512] ..16777216
    float* H1  = ws + 16777216;                    // [128][512]
    float* FP2 = ws + 16842752;                    // [16][128][512]
    float* H2  = ws + 17891328;                    // [128][512] ..17956864
    _Float16* B1h = (_Float16*)(ws + 17956864);    // 1024 halves (w1 pack)
    _Float16* B1l = (_Float16*)(ws + 17957376);
    _Float16* Bh = (_Float16*)(ws + 20971520);     // 285696 halves (w2..w6)
    _Float16* Bl = (_Float16*)(ws + 21114368);     // ends 21257216 fl = 85 MB

    hipLaunchKernelGGL(k_wrepackm, dim3(1120), dim3(256), 0, stream,
                       w1, w2, w3, w4, w5, w6, Bh, Bl, B1h, B1l);

    // conv1+conv2+pool4: grid = 8x8 tiles x 128 batch
    hipLaunchKernelGGL(k_conv12, dim3(64, 128), dim3(256), 0, stream,
                       img, b1, B1h, B1l, Bh + 0, Bl + 0, b2, P1h);
    // conv3: M=131072, K=288, COUT=64 (CIN=32 -> BK=32)
    hipLaunchKernelGGL((k_mgemm<32, 64, 32, false, 32, false>), dim3(1024, 1), dim3(256), 0, stream,
                       P1h, Bh + 9216, Bl + 9216, b3, A3h, nullptr);
    // conv4 + fused 2x2 pool -> P2 directly: K=576, BK=64
    hipLaunchKernelGGL((k_mgemm<64, 64, 32, false, 64, true>), dim3(1024, 1), dim3(256), 0, stream,
                       A3h, Bh + 27648, Bl + 27648, b4, P2h, nullptr);
    // conv5: M=32768, K=576, COUT=128, BK=64
    hipLaunchKernelGGL((k_mgemm<64, 128, 16, false, 64, false>), dim3(256, 2), dim3(256), 0, stream,
                       P2h, Bh + 64512, Bl + 64512, b5, A5h, nullptr);
    // conv6: K=1152, hi/lo out for MFMA FC1, BK=64
    hipLaunchKernelGGL((k_mgemm<128, 128, 16, true, 64, false>), dim3(256, 2), dim3(256), 0, stream,
                       A5h, Bh + 138240, Bl + 138240, b6, A6h, A6l);
    // FC1 on MFMA: grid (8 n-blocks, 64 k-chunks)
    hipLaunchKernelGGL(k_fc1m, dim3(8, 64), dim3(256), 0, stream,
                       A6h, A6l, wl1, FP1);
    hipLaunchKernelGGL(k_fc_reduce<64>, dim3(64), dim3(256), 0, stream, FP1, bl1, H1);
    hipLaunchKernelGGL((k_fc_partial<512, 32, 4, false>), dim3(8, 16), dim3(256), 0, stream,
                       H1, wl2, FP2);
    hipLaunchKernelGGL(k_fc_reduce<16>, dim3(64), dim3(256), 0, stream, FP2, bl2, H2);
    hipLaunchKernelGGL(k_final, dim3(128), dim3(256), 0, stream,
                       H2, wl3, bl3, nois, img, out);
}

// Round 14
// 471.645 us; speedup vs baseline: 1.0293x; 1.0293x over previous
//
#include <hip/hip_runtime.h>
#include <math.h>

typedef _Float16 __attribute__((ext_vector_type(8))) half8_t;
typedef _Float16 __attribute__((ext_vector_type(4))) half4_t;
typedef _Float16 __attribute__((ext_vector_type(2))) half2_t;
typedef float    __attribute__((ext_vector_type(4))) float4_t;

// ---------------------------------------------------------------------------
// Kernel 1: fully-MFMA conv1 + conv2 + maxpool4 (block = 16x16 output tile).
// Phase A: img -> simg (fp32 LDS halo-2) -> im2col into
//   C1h[slot=k/8][pos=18*18][j=k&7] fp16 HI ONLY (R8).
// Phase B: conv1 GEMM transposed: M=32 ch, N=324 pos, K=32, 2-term (wh+wl)*xh.
// Phase C: epilogue -> C1h overwrite, HI ONLY (R10).
// Phase D: conv2 implicit GEMM 2-term (ah*bh + ah*bl) + thread-local 4x4 pool.
// LDS = 6000(simg) + 21504(C1h) = 27.5 KB -> 5 blocks/CU.
// POSP=336 (mult of 8: swizzle bijective, R2); idx per (slot,pos) (R5).
// [R14 NOTE: exact revert to the R11 configuration (best measured 470.8us);
//  R12/R13's hi-only conv chain regressed the latency-bound conv bucket.]
// ---------------------------------------------------------------------------
#define POSP 336

__device__ __forceinline__ int c1idx(int slot, int pos) {
    return ((slot * POSP + pos) * 8) ^ (((pos >> 3) & 7) << 3);
}

__global__ __launch_bounds__(256, 5)
void k_conv12(const float* __restrict__ img, const float* __restrict__ b1,
              const _Float16* __restrict__ B1h, const _Float16* __restrict__ B1l,
              const _Float16* __restrict__ B2h, const _Float16* __restrict__ B2l,
              const float* __restrict__ b2,
              _Float16* __restrict__ P1h, _Float16* __restrict__ P1l)
{
    __shared__ float simg[3 * 20 * 25];                    // input halo-2
    __shared__ __align__(16) _Float16 C1h[4 * POSP * 8];   // A, then conv1 out

    const int t  = threadIdx.x;
    const int bt = blockIdx.x;
    const int b  = blockIdx.y;
    const int ty = bt >> 3, tx = bt & 7;
    const int oy = ty * 16, ox = tx * 16;

    // ---- Phase A1: stage fp32 halo (bounds-checked ONCE, zero-padded) ----
    for (int i = t; i < 1500; i += 256) {
        const int ci = i / 500, r = i - ci * 500;
        const int yy = r / 25, xx = r - yy * 25;
        const int gy = oy - 2 + yy, gx = ox - 2 + xx;
        float v = 0.f;
        if ((unsigned)gy < 128u && (unsigned)gx < 128u)
            v = img[((b * 3 + ci) * 128 + gy) * 128 + gx];
        simg[i] = v;
    }
    __syncthreads();

    // ---- Phase A2: im2col simg -> C1h (hi only; compile-time tap offsets) --
    #pragma unroll
    for (int hf = 0; hf < 2; ++hf) {
        const int pos = hf * 256 + t;
        if (pos < POSP) {
            const bool val = pos < 324;
            int sb = 0;
            if (val) {
                const int py = pos / 18, px = pos - py * 18;
                sb = py * 25 + px;
            }
            #pragma unroll
            for (int s = 0; s < 4; ++s) {
                half8_t vh = {0,0,0,0,0,0,0,0};
                if (val) {
                    #pragma unroll
                    for (int j = 0; j < 8; ++j) {
                        const int k = s * 8 + j;
                        if (k < 27) {
                            const int ci = k / 9, tap = k - ci * 9;   // const
                            const int dy = tap / 3, dx = tap - dy * 3; // const
                            vh[j] = (_Float16)simg[sb + (ci * 20 + dy) * 25 + dx];
                        }
                    }
                }
                *(half8_t*)(&C1h[c1idx(s, pos)]) = vh;
            }
        }
    }
    __syncthreads();

    const int wv   = __builtin_amdgcn_readfirstlane(t >> 6);
    const int lane = t & 63;
    const int fr   = lane >> 4;
    const int ml   = lane & 15;

    // ---- Phase B: conv1 MFMA, transposed, 2-term: D[ch][pos] = w @ xh ----
    half8_t wAh[2], wAl[2];
    #pragma unroll
    for (int mt = 0; mt < 2; ++mt) {
        wAh[mt] = *(const half8_t*)(B1h + (mt * 64 + lane) * 8);
        wAl[mt] = *(const half8_t*)(B1l + (mt * 64 + lane) * 8);
    }
    float4_t acc1[6][2];
    #pragma unroll
    for (int q = 0; q < 6; ++q)
        #pragma unroll
        for (int mt = 0; mt < 2; ++mt)
            acc1[q][mt] = (float4_t){0.f, 0.f, 0.f, 0.f};

    #pragma unroll
    for (int q = 0; q < 6; ++q) {
        const int nt = wv + q * 4;
        if (nt < 21) {
            const int ri = c1idx(fr, nt * 16 + ml);
            const half8_t dh = *(const half8_t*)(&C1h[ri]);
            #pragma unroll
            for (int mt = 0; mt < 2; ++mt) {
                acc1[q][mt] = __builtin_amdgcn_mfma_f32_16x16x32_f16(wAh[mt], dh, acc1[q][mt], 0, 0, 0);
                acc1[q][mt] = __builtin_amdgcn_mfma_f32_16x16x32_f16(wAl[mt], dh, acc1[q][mt], 0, 0, 0);
            }
        }
    }
    __syncthreads();          // all A reads done; buffer reusable

    // ---- Phase C: epilogue -> overwrite C1h (hi only). ----
    const float4_t bA = *(const float4_t*)(b1 + fr * 4);
    const float4_t bB = *(const float4_t*)(b1 + 16 + fr * 4);
    #pragma unroll
    for (int q = 0; q < 6; ++q) {
        const int nt = wv + q * 4;
        if (nt < 21) {
            const int pos = nt * 16 + ml;
            if (pos < 324) {
                const int py = pos / 18, px = pos - py * 18;
                const int gy = oy + py - 1, gx = ox + px - 1;
                const bool ok = (unsigned)gy < 128u && (unsigned)gx < 128u;
                #pragma unroll
                for (int mt = 0; mt < 2; ++mt) {
                    const int slot = mt * 2 + (fr >> 1);
                    const int wi = c1idx(slot, pos) + (fr & 1) * 4;
                    const float4_t bb = mt ? bB : bA;
                    half4_t oh;
                    #pragma unroll
                    for (int r = 0; r < 4; ++r) {
                        const float v = ok ? fmaxf(acc1[q][mt][r] + bb[r], 0.f) : 0.f;
                        oh[r] = (_Float16)v;
                    }
                    *(half4_t*)(&C1h[wi]) = oh;
                }
            }
        }
    }
    __syncthreads();

    // ---- Phase D: conv2 implicit-GEMM 2-term, wave wv owns rows wv*4.. ----
    float4_t acc[4][2];
    #pragma unroll
    for (int i = 0; i < 4; ++i)
        #pragma unroll
        for (int nt = 0; nt < 2; ++nt)
            acc[i][nt] = (float4_t){0.f, 0.f, 0.f, 0.f};

    #pragma unroll 1
    for (int tap = 0; tap < 9; ++tap) {
        const int dy = tap / 3, dx = tap - dy * 3;
        half8_t bh[2], bl[2];
        #pragma unroll
        for (int nt = 0; nt < 2; ++nt) {
            const int bo = ((tap * 2 + nt) * 64 + lane) * 8;
            bh[nt] = *(const half8_t*)(B2h + bo);
            bl[nt] = *(const half8_t*)(B2l + bo);
        }
        half8_t ah[4];
        #pragma unroll
        for (int i = 0; i < 4; ++i) {
            const int pos = (wv * 4 + i + dy) * 18 + ml + dx;
            ah[i] = *(const half8_t*)(&C1h[c1idx(fr, pos)]);
        }
        #pragma unroll
        for (int nt = 0; nt < 2; ++nt)
            #pragma unroll
            for (int i = 0; i < 4; ++i)
                acc[i][nt] = __builtin_amdgcn_mfma_f32_16x16x32_f16(ah[i], bh[nt], acc[i][nt], 0, 0, 0);
        #pragma unroll
        for (int nt = 0; nt < 2; ++nt)
            #pragma unroll
            for (int i = 0; i < 4; ++i)
                acc[i][nt] = __builtin_amdgcn_mfma_f32_16x16x32_f16(ah[i], bl[nt], acc[i][nt], 0, 0, 0);
    }

    // ---- maxpool4 (thread-local) + bias + relu + hi/lo store ----
    const int py = ty * 4 + wv;
    const int px = tx * 4 + fr;
    #pragma unroll
    for (int nt = 0; nt < 2; ++nt) {
        float m = -1e30f;
        #pragma unroll
        for (int i = 0; i < 4; ++i)
            #pragma unroll
            for (int r = 0; r < 4; ++r)
                m = fmaxf(m, acc[i][nt][r]);
        const int oc = nt * 16 + ml;
        const float v = fmaxf(m + b2[oc], 0.f);
        const _Float16 h = (_Float16)v;
        const int base = ((b * 32 + py) * 32 + px) * 32 + oc;
        P1h[base] = h;
        P1l[base] = (_Float16)(v - (float)h);
    }
}

// ---------------------------------------------------------------------------
// Weight repack: fp16 hi/lo MFMA-fragment packs for w2..w6 (+ w1, K padded
// 27->32). Frag order: Bh[((c*NT + ntg)*64 + lane)*8 + j], element B[k][n]:
//   n = ntg*16 + (lane&15), k = c*32 + (lane>>4)*8 + j.
// ---------------------------------------------------------------------------
__global__ void k_wrepackm(const float* __restrict__ w1, const float* __restrict__ w2,
                           const float* __restrict__ w3, const float* __restrict__ w4,
                           const float* __restrict__ w5, const float* __restrict__ w6,
                           _Float16* __restrict__ Bh, _Float16* __restrict__ Bl,
                           _Float16* __restrict__ B1h, _Float16* __restrict__ B1l)
{
    int idx = blockIdx.x * 256 + threadIdx.x;
    if (idx >= 285696) {
        const int i = idx - 285696;
        if (i >= 1024) return;
        const int ntg = i >> 9, rr = i & 511;
        const int lane = rr >> 3, j = rr & 7;
        const int k = (lane >> 4) * 8 + j;
        const int n = ntg * 16 + (lane & 15);
        const float v = (k < 27) ? w1[n * 27 + k] : 0.f;
        const _Float16 h = (_Float16)v;
        B1h[i] = h;
        B1l[i] = (_Float16)(v - (float)h);
        return;
    }
    const float* w; int CIN, COUT, off;
    if (idx < 9216)        { w = w2; CIN = 32;  COUT = 32;  off = 0; }
    else if (idx < 27648)  { idx -= 9216;   w = w3; CIN = 32;  COUT = 64;  off = 9216; }
    else if (idx < 64512)  { idx -= 27648;  w = w4; CIN = 64;  COUT = 64;  off = 27648; }
    else if (idx < 138240) { idx -= 64512;  w = w5; CIN = 64;  COUT = 128; off = 64512; }
    else                   { idx -= 138240; w = w6; CIN = 128; COUT = 128; off = 138240; }
    const int NT  = COUT / 16;
    const int c   = idx / (NT * 512);
    const int r   = idx - c * NT * 512;
    const int ntg = r >> 9;
    const int rr  = r & 511;
    const int lane = rr >> 3, j = rr & 7;
    const int k   = c * 32 + (lane >> 4) * 8 + j;
    const int tap = k / CIN, ci = k - tap * CIN;
    const int oc  = ntg * 16 + (lane & 15);
    const float v = w[(oc * CIN + ci) * 9 + tap];
    const _Float16 h = (_Float16)v;
    Bh[off + idx] = h;
    Bl[off + idx] = (_Float16)(v - (float)h);
}

// ---------------------------------------------------------------------------
// MFMA implicit-GEMM conv3x3. BM=128, BN=64; 4 waves = 2 m-tiles x 4 n-tiles.
// BK=64 for CIN>=64 (two 32-k chunks per barrier pair). conv3 BK=32.
// Hi/lo dual-plane activations, 3-term split (fp32-class).
// ---------------------------------------------------------------------------
template<int CIN, int COUT, int HW, bool OUTF32, int BK>
__global__ __launch_bounds__(256, 2)
void k_mgemm(const _Float16* __restrict__ inh, const _Float16* __restrict__ inl,
             const _Float16* __restrict__ Bh, const _Float16* __restrict__ Bl,
             const float* __restrict__ bias,
             _Float16* __restrict__ outh, _Float16* __restrict__ outl,
             float* __restrict__ outf)
{
    constexpr int NCH = CIN * 9 / BK;
    constexpr int SUB = BK / 32;
    constexpr int NT  = COUT / 16;
    constexpr int LOG = (HW == 32) ? 5 : 4;
    constexpr int PS  = BK + ((BK == 64) ? 4 : 8);
    constexpr int NJ  = BK / 16;          // staging iterations
    constexpr int GPR = BK / 8;           // half8 groups per row
    __shared__ _Float16 Ash[128 * PS];
    __shared__ _Float16 Asl[128 * PS];

    const int t    = threadIdx.x;
    const int wv   = t >> 6;
    const int lane = t & 63;
    const int m0   = blockIdx.x * 128;
    const int nb   = blockIdx.y;

    int sm[NJ], sg[NJ], sb[NJ], sy[NJ], sx[NJ];
    #pragma unroll
    for (int j = 0; j < NJ; ++j) {
        const int q = t + 256 * j;
        sm[j] = q / GPR;
        sg[j] = q - sm[j] * GPR;
        const int m  = m0 + sm[j];
        const int yx = m & (HW * HW - 1);
        sb[j] = m >> (2 * LOG);
        sy[j] = yx >> LOG;
        sx[j] = yx & (HW - 1);
    }

    const int mt0 = wv * 2;
    const int fr  = lane >> 4;
    const int ml  = lane & 15;

    float4_t acc[2][4];
    #pragma unroll
    for (int mt = 0; mt < 2; ++mt)
        #pragma unroll
        for (int tn = 0; tn < 4; ++tn)
            acc[mt][tn] = (float4_t){0.f, 0.f, 0.f, 0.f};

    #pragma unroll 1
    for (int ch = 0; ch < NCH; ++ch) {
        const int kb  = ch * BK;
        const int tap = kb / CIN;
        const int c0  = kb - tap * CIN;
        const int dy  = tap / 3 - 1, dx = tap - (tap / 3) * 3 - 1;

        if (ch) __syncthreads();
        #pragma unroll
        for (int j = 0; j < NJ; ++j) {
            const int iy = sy[j] + dy, ix = sx[j] + dx;
            half8_t vh = {0, 0, 0, 0, 0, 0, 0, 0};
            half8_t vl = {0, 0, 0, 0, 0, 0, 0, 0};
            if ((unsigned)iy < (unsigned)HW && (unsigned)ix < (unsigned)HW) {
                const int o = ((sb[j] * HW + iy) * HW + ix) * CIN + c0 + sg[j] * 8;
                vh = *(const half8_t*)(inh + o);
                vl = *(const half8_t*)(inl + o);
            }
            *(half8_t*)(&Ash[sm[j] * PS + sg[j] * 8]) = vh;
            *(half8_t*)(&Asl[sm[j] * PS + sg[j] * 8]) = vl;
        }
        __syncthreads();

        #pragma unroll
        for (int ss = 0; ss < SUB; ++ss) {
            half8_t ah[2], al[2];
            #pragma unroll
            for (int mt = 0; mt < 2; ++mt) {
                const int mr = (mt0 + mt) * 16 + ml;
                ah[mt] = *(const half8_t*)(&Ash[mr * PS + ss * 32 + fr * 8]);
                al[mt] = *(const half8_t*)(&Asl[mr * PS + ss * 32 + fr * 8]);
            }
            half8_t bh[4], bl[4];
            #pragma unroll
            for (int tn = 0; tn < 4; ++tn) {
                const int bo = (((ch * SUB + ss) * NT + nb * 4 + tn) * 64 + lane) * 8;
                bh[tn] = *(const half8_t*)(Bh + bo);
                bl[tn] = *(const half8_t*)(Bl + bo);
            }
            #pragma unroll
            for (int tn = 0; tn < 4; ++tn)
                #pragma unroll
                for (int mt = 0; mt < 2; ++mt)
                    acc[mt][tn] = __builtin_amdgcn_mfma_f32_16x16x32_f16(ah[mt], bh[tn], acc[mt][tn], 0, 0, 0);
            #pragma unroll
            for (int tn = 0; tn < 4; ++tn)
                #pragma unroll
                for (int mt = 0; mt < 2; ++mt)
                    acc[mt][tn] = __builtin_amdgcn_mfma_f32_16x16x32_f16(al[mt], bh[tn], acc[mt][tn], 0, 0, 0);
            #pragma unroll
            for (int tn = 0; tn < 4; ++tn)
                #pragma unroll
                for (int mt = 0; mt < 2; ++mt)
                    acc[mt][tn] = __builtin_amdgcn_mfma_f32_16x16x32_f16(ah[mt], bl[tn], acc[mt][tn], 0, 0, 0);
            // (al,bl) term dropped: <= 2^-22 relative contribution.
        }
    }

    // epilogue: C/D frag col=lane&15, row=(lane>>4)*4+reg  [guide m89/m91]
    #pragma unroll
    for (int mt = 0; mt < 2; ++mt)
        #pragma unroll
        for (int tn = 0; tn < 4; ++tn) {
            const int oc = nb * 64 + tn * 16 + ml;
            const float bv = bias[oc];
            #pragma unroll
            for (int r = 0; r < 4; ++r) {
                const int m = m0 + (mt0 + mt) * 16 + fr * 4 + r;
                const float v = fmaxf(acc[mt][tn][r] + bv, 0.f);
                const _Float16 h = (_Float16)v;
                outh[m * COUT + oc] = h;
                outl[m * COUT + oc] = (_Float16)(v - (float)h);
            }
        }
}

// ---------------------------------------------------------------------------
// MFMA FC1: H1-partials = A[128 x 32768] @ wl1[32768 x 512], split-K.
// A from fp16 hi/lo A6 planes; W fp32 direct from wl1 (perm folded), hi/lo
// converted in-LDS. 3-term split = fp32-class. Partials fp32.
// ---------------------------------------------------------------------------
__global__ __launch_bounds__(256, 2)
void k_fc1m(const _Float16* __restrict__ A6h, const _Float16* __restrict__ A6l,
            const float* __restrict__ wl1, float* __restrict__ part)
{
    __shared__ __align__(16) _Float16 Ah[128 * 68];
    __shared__ __align__(16) _Float16 Al[128 * 68];
    __shared__ __align__(16) _Float16 Wh[64 * 68];
    __shared__ __align__(16) _Float16 Wl[64 * 68];

    const int t    = threadIdx.x;
    const int wv   = t >> 6;
    const int lane = t & 63;
    const int fr   = lane >> 4;
    const int ml   = lane & 15;
    const int n0   = blockIdx.x * 64;
    const int kc   = blockIdx.y;

    float4_t acc[2][4];
    #pragma unroll
    for (int mt = 0; mt < 2; ++mt)
        #pragma unroll
        for (int tn = 0; tn < 4; ++tn)
            acc[mt][tn] = (float4_t){0.f, 0.f, 0.f, 0.f};

    #pragma unroll 1
    for (int it = 0; it < 8; ++it) {
        const int kb = kc * 512 + it * 64;
        const int yx = kb >> 7;           // 64-k window never crosses yx
        const int c0 = kb & 127;

        if (it) __syncthreads();
        // stage A [128 b][64 k] hi/lo (coalesced 128B runs per b)
        #pragma unroll
        for (int q = 0; q < 4; ++q) {
            const int lin = q * 256 + t;
            const int bb = lin >> 3, g = lin & 7;
            const int src = (bb * 256 + yx) * 128 + c0 + g * 8;
            *(half8_t*)(&Ah[bb * 68 + g * 8]) = *(const half8_t*)(A6h + src);
            *(half8_t*)(&Al[bb * 68 + g * 8]) = *(const half8_t*)(A6l + src);
        }
        // stage W: wl1 row kref=(c0+kk)*256+yx, 64 n fp32 -> hi/lo [n][68]
        {
            const int kk = t >> 2;
            const float* wrow = wl1 + ((c0 + kk) * 256 + yx) * 512 + n0;
            #pragma unroll
            for (int q = 0; q < 4; ++q) {
                const int nq = (t & 3) + q * 4;
                const float4 v = *(const float4*)(wrow + nq * 4);
                #pragma unroll
                for (int e = 0; e < 4; ++e) {
                    const int n = nq * 4 + e;
                    const float w = (&v.x)[e];
                    const _Float16 h = (_Float16)w;
                    Wh[n * 68 + kk] = h;
                    Wl[n * 68 + kk] = (_Float16)(w - (float)h);
                }
            }
        }
        __syncthreads();

        #pragma unroll
        for (int ss = 0; ss < 2; ++ss) {
            half8_t ah[2], al[2];
            #pragma unroll
            for (int mt = 0; mt < 2; ++mt) {
                const int bb = (wv * 2 + mt) * 16 + ml;
                ah[mt] = *(const half8_t*)(&Ah[bb * 68 + ss * 32 + fr * 8]);
                al[mt] = *(const half8_t*)(&Al[bb * 68 + ss * 32 + fr * 8]);
            }
            half8_t bh[4], bl[4];
            #pragma unroll
            for (int tn = 0; tn < 4; ++tn) {
                const int nn = tn * 16 + ml;
                bh[tn] = *(const half8_t*)(&Wh[nn * 68 + ss * 32 + fr * 8]);
                bl[tn] = *(const half8_t*)(&Wl[nn * 68 + ss * 32 + fr * 8]);
            }
            #pragma unroll
            for (int tn = 0; tn < 4; ++tn)
                #pragma unroll
                for (int mt = 0; mt < 2; ++mt)
                    acc[mt][tn] = __builtin_amdgcn_mfma_f32_16x16x32_f16(ah[mt], bh[tn], acc[mt][tn], 0, 0, 0);
            #pragma unroll
            for (int tn = 0; tn < 4; ++tn)
                #pragma unroll
                for (int mt = 0; mt < 2; ++mt)
                    acc[mt][tn] = __builtin_amdgcn_mfma_f32_16x16x32_f16(al[mt], bh[tn], acc[mt][tn], 0, 0, 0);
            #pragma unroll
            for (int tn = 0; tn < 4; ++tn)
                #pragma unroll
                for (int mt = 0; mt < 2; ++mt)
                    acc[mt][tn] = __builtin_amdgcn_mfma_f32_16x16x32_f16(ah[mt], bl[tn], acc[mt][tn], 0, 0, 0);
        }
    }

    // partials (no bias/relu -- reduce applies them)
    const long pb = (long)kc * 65536;
    #pragma unroll
    for (int mt = 0; mt < 2; ++mt)
        #pragma unroll
        for (int tn = 0; tn < 4; ++tn) {
            const int nn = n0 + tn * 16 + ml;
            #pragma unroll
            for (int r = 0; r < 4; ++r) {
                const int m = (wv * 2 + mt) * 16 + fr * 4 + r;
                part[pb + m * 512 + nn] = acc[mt][tn][r];
            }
        }
}

// ---------------------------------------------------------------------------
// 2x2 maxpool on dual fp16 planes, NHWC [128][32][32][64] -> [128][16][16][64]
// ---------------------------------------------------------------------------
__global__ __launch_bounds__(256)
void k_pool2h(const _Float16* __restrict__ inh, const _Float16* __restrict__ inl,
              _Float16* __restrict__ outh, _Float16* __restrict__ outl)
{
    const int g = blockIdx.x * 256 + threadIdx.x;
    const int c4 = g & 15, xo = (g >> 4) & 15, yo = (g >> 8) & 15, b = g >> 12;
    const int base = ((b * 32 + yo * 2) * 32 + xo * 2) * 64 + c4 * 4;
    const int offs[4] = {0, 64, 2048, 2112};
    float mx[4] = {-1e30f, -1e30f, -1e30f, -1e30f};
    #pragma unroll
    for (int cnd = 0; cnd < 4; ++cnd) {
        const half4_t h = *(const half4_t*)(inh + base + offs[cnd]);
        const half4_t l = *(const half4_t*)(inl + base + offs[cnd]);
        #pragma unroll
        for (int e = 0; e < 4; ++e)
            mx[e] = fmaxf(mx[e], (float)h[e] + (float)l[e]);
    }
    half4_t oh, ol;
    #pragma unroll
    for (int e = 0; e < 4; ++e) {
        const _Float16 h = (_Float16)mx[e];
        oh[e] = h;
        ol[e] = (_Float16)(mx[e] - (float)h);
    }
    const int ob = ((b * 16 + yo) * 16 + xo) * 64 + c4 * 4;
    *(half4_t*)(outh + ob) = oh;
    *(half4_t*)(outl + ob) = ol;
}

// ---------------------------------------------------------------------------
// Split-K FC partial (fp32): A[128 x K] @ B[K x 512] -> part[ky][128][512]
// (FC2 only)
// ---------------------------------------------------------------------------
template<int LDA, int KCHUNK, int TN, bool PERM>
__global__ __launch_bounds__(256, 2)
void k_fc_partial(const float* __restrict__ A, const float* __restrict__ Bw,
                  float* __restrict__ part)
{
    constexpr int BN = 16 * TN;
    constexpr int SA = 140;
    constexpr int SB = (BN == 128) ? 140 : 68;
    __shared__ __align__(16) float As[32 * SA];
    __shared__ __align__(16) float Bs[32 * SB];
    const int t  = threadIdx.x;
    const int tm = t >> 4, tn = t & 15;
    const int n0 = blockIdx.x * BN;
    const int k0 = blockIdx.y * KCHUNK;

    float acc[8][TN];
    #pragma unroll
    for (int r = 0; r < 8; ++r)
        #pragma unroll
        for (int c = 0; c < TN; ++c) acc[r][c] = 0.f;

    #pragma unroll 1
    for (int ks = 0; ks < KCHUNK / 32; ++ks) {
        if (ks) __syncthreads();
        const int kb = k0 + ks * 32;
        for (int i = t; i < 4096; i += 256) {
            const int m = i >> 5, kk = i & 31;
            As[kk * SA + m + ((m >> 5) << 2)] = A[m * LDA + kb + kk];
        }
        for (int i = t; i < 32 * BN; i += 256) {
            const int kk = i / BN, n = i - kk * BN;
            const int krow = kb + kk;
            const int kref = PERM ? ((krow & 127) * 256 + (krow >> 7)) : krow;
            Bs[kk * SB + n + ((n >> 5) << 2)] = Bw[kref * 512 + n0 + n];
        }
        __syncthreads();
        #pragma unroll 2
        for (int kk = 0; kk < 32; ++kk) {
            const float* ap = &As[kk * SA + tm * 8 + ((tm >> 2) << 2)];
            const float* bp = &Bs[kk * SB + tn * TN + (((tn * TN) >> 5) << 2)];
            float a[8], bb[TN];
            #pragma unroll
            for (int q = 0; q < 8; q += 4) {
                const float4 v = *(const float4*)(ap + q);
                a[q] = v.x; a[q + 1] = v.y; a[q + 2] = v.z; a[q + 3] = v.w;
            }
            #pragma unroll
            for (int q = 0; q < TN; q += 4) {
                const float4 v = *(const float4*)(bp + q);
                bb[q] = v.x; bb[q + 1] = v.y; bb[q + 2] = v.z; bb[q + 3] = v.w;
            }
            #pragma unroll
            for (int r = 0; r < 8; ++r)
                #pragma unroll
                for (int c = 0; c < TN; ++c)
                    acc[r][c] = fmaf(a[r], bb[c], acc[r][c]);
        }
    }

    const long pb = (long)blockIdx.y * 65536;
    #pragma unroll
    for (int r = 0; r < 8; ++r)
        #pragma unroll
        for (int c = 0; c < TN; ++c)
            part[pb + (tm * 8 + r) * 512 + n0 + tn * TN + c] = acc[r][c];
}

template<int NS>
__global__ __launch_bounds__(256)
void k_fc_reduce(const float* __restrict__ part, const float* __restrict__ bias,
                 float* __restrict__ H)
{
    const int f = (blockIdx.x * 256 + threadIdx.x) * 4;
    const int m = f >> 9, n = f & 511;
    float s0 = 0.f, s1 = 0.f, s2 = 0.f, s3 = 0.f;
    #pragma unroll 4
    for (int q = 0; q < NS; ++q) {
        const float* p = &part[(q * 128 + m) * 512 + n];
        s0 += p[0]; s1 += p[1]; s2 += p[2]; s3 += p[3];
    }
    H[f]     = fmaxf(s0 + bias[n],     0.f);
    H[f + 1] = fmaxf(s1 + bias[n + 1], 0.f);
    H[f + 2] = fmaxf(s2 + bias[n + 2], 0.f);
    H[f + 3] = fmaxf(s3 + bias[n + 3], 0.f);
}

// ---------------------------------------------------------------------------
// Final: FC3 + sampling + patch gather
// ---------------------------------------------------------------------------
__device__ __forceinline__ float softplusf(float x) {
    return (x > 20.f) ? x : log1pf(expf(x));
}
__device__ __forceinline__ float sigmoidf_(float x) {
    return 1.f / (1.f + expf(-x));
}

__global__ __launch_bounds__(256)
void k_final(const float* __restrict__ H2, const float* __restrict__ wl3,
             const float* __restrict__ bl3, const float* __restrict__ noise,
             const float* __restrict__ img, float* __restrict__ outp)
{
    __shared__ float h2[512];
    __shared__ float red[144];
    __shared__ float prep[36];
    __shared__ int ptsh[12], ptsw[12];
    const int b = blockIdx.x, t = threadIdx.x;

    h2[t]       = H2[b * 512 + t];
    h2[t + 256] = H2[b * 512 + 256 + t];
    __syncthreads();

    if (t < 144) {
        const int n = t >> 2, q = t & 3;
        float s = 0.f;
        for (int k = q * 128; k < q * 128 + 128; ++k)
            s = fmaf(h2[k], wl3[k * 36 + n], s);
        red[t] = s;
    }
    __syncthreads();
    if (t < 36)
        prep[t] = red[t * 4] + red[t * 4 + 1] + red[t * 4 + 2] + red[t * 4 + 3] + bl3[t];
    __syncthreads();

    if (t < 12) {
        const float m0 = prep[t * 3], m1 = prep[t * 3 + 1], sv = prep[t * 3 + 2];
        const float sig = softplusf(sv + 2.0f) * 128.f + 1e-7f;
        const float n0 = noise[(b * 12 + t) * 2], n1 = noise[(b * 12 + t) * 2 + 1];
        const float sa0 = m0 + sig * n0;
        const float sa1 = m1 + sig * n1;
        int p0 = (int)rintf(sigmoidf_(sa0) * 111.f);
        int p1 = (int)rintf(sigmoidf_(sa1) * 111.f);
        p0 = min(max(p0, 0), 111);
        p1 = min(max(p1, 0), 111);
        const int RM = 1179648;
        outp[RM        + (b * 12 + t) * 2 + 0] = m0;
        outp[RM        + (b * 12 + t) * 2 + 1] = m1;
        outp[RM + 3072 + (b * 12 + t) * 2 + 0] = sig;
        outp[RM + 3072 + (b * 12 + t) * 2 + 1] = sig;
        outp[RM + 6144 + (b * 12 + t) * 2 + 0] = sa0;
        outp[RM + 6144 + (b * 12 + t) * 2 + 1] = sa1;
        ptsh[t] = p0;
        ptsw[t] = p1;
    }
    __syncthreads();

    for (int i = t; i < 9216; i += 256) {
        const int g  = i / 768, r = i - g * 768;
        const int c  = r >> 8, r2 = r & 255;
        const int y  = r2 >> 4, x = r2 & 15;
        outp[b * 9216 + i] = img[((b * 3 + c) * 128 + ptsh[g] + y) * 128 + (ptsw[g] + x)];
    }
}

// ---------------------------------------------------------------------------
extern "C" void kernel_launch(void* const* d_in, const int* in_sizes, int n_in,
                              void* d_out, int out_size, void* d_ws, size_t ws_size,
                              hipStream_t stream)
{
    const float* img  = (const float*)d_in[0];
    const float* nois = (const float*)d_in[1];
    const float* w1 = (const float*)d_in[2];  const float* b1 = (const float*)d_in[3];
    const float* w2 = (const float*)d_in[4];  const float* b2 = (const float*)d_in[5];
    const float* w3 = (const float*)d_in[6];  const float* b3 = (const float*)d_in[7];
    const float* w4 = (const float*)d_in[8];  const float* b4 = (const float*)d_in[9];
    const float* w5 = (const float*)d_in[10]; const float* b5 = (const float*)d_in[11];
    const float* w6 = (const float*)d_in[12]; const float* b6 = (const float*)d_in[13];
    const float* wl1 = (const float*)d_in[14]; const float* bl1 = (const float*)d_in[15];
    const float* wl2 = (const float*)d_in[16]; const float* bl2 = (const float*)d_in[17];
    const float* wl3 = (const float*)d_in[18]; const float* bl3 = (const float*)d_in[19];
    float* out = (float*)d_out;
    float* ws  = (float*)d_ws;

    // workspace (float units). Activation regions span [0 .. 20971520).
    _Float16* P1h = (_Float16*)(ws);               // [128*32*32*32] halves
    _Float16* P1l = (_Float16*)(ws + 2097152);
    _Float16* A3h = (_Float16*)(ws + 4194304);     // [128*32*32*64]
    _Float16* A3l = (_Float16*)(ws + 8388608);
    _Float16* A4h = (_Float16*)(ws + 12582912);    // [128*32*32*64]
    _Float16* A4l = (_Float16*)(ws + 16777216);    // ..20971520
    _Float16* P2h = (_Float16*)(ws);               // [128*16*16*64] (P1 dead)
    _Float16* P2l = (_Float16*)(ws + 1048576);
    _Float16* A5h = (_Float16*)(ws + 4194304);     // [128*16*16*128] (A3 dead)
    _Float16* A5l = (_Float16*)(ws + 6291456);
    _Float16* A6h = (_Float16*)(ws + 8388608);     // [32768*128] halves
    _Float16* A6l = (_Float16*)(ws + 10485760);
    float* FP1 = ws + 12582912;                    // [64][128][512] (A4h dead)
    float* H1  = ws + 16777216;                    // [128][512]     (A4l dead)
    float* FP2 = ws + 16842752;                    // [16][128][512]
    float* H2  = ws + 17891328;                    // [128][512]
    _Float16* B1h = (_Float16*)(ws + 17956864);    // 1024 halves (w1 pack)
    _Float16* B1l = (_Float16*)(ws + 17957376);
    _Float16* Bh = (_Float16*)(ws + 20971520);     // 285696 halves (w2..w6)
    _Float16* Bl = (_Float16*)(ws + 21114368);     // ends 21257216 fl = 85 MB

    hipLaunchKernelGGL(k_wrepackm, dim3(1120), dim3(256), 0, stream,
                       w1, w2, w3, w4, w5, w6, Bh, Bl, B1h, B1l);

    // conv1+conv2+pool4: grid = 8x8 tiles x 128 batch
    hipLaunchKernelGGL(k_conv12, dim3(64, 128), dim3(256), 0, stream,
                       img, b1, B1h, B1l, Bh + 0, Bl + 0, b2, P1h, P1l);
    // conv3: M=131072, K=288, COUT=64 (CIN=32 -> BK=32)
    hipLaunchKernelGGL((k_mgemm<32, 64, 32, false, 32>), dim3(1024, 1), dim3(256), 0, stream,
                       P1h, P1l, Bh + 9216, Bl + 9216, b3, A3h, A3l, nullptr);
    // conv4: K=576, BK=64
    hipLaunchKernelGGL((k_mgemm<64, 64, 32, false, 64>), dim3(1024, 1), dim3(256), 0, stream,
                       A3h, A3l, Bh + 27648, Bl + 27648, b4, A4h, A4l, nullptr);
    hipLaunchKernelGGL(k_pool2h, dim3(2048), dim3(256), 0, stream, A4h, A4l, P2h, P2l);
    // conv5: M=32768, K=576, COUT=128, BK=64
    hipLaunchKernelGGL((k_mgemm<64, 128, 16, false, 64>), dim3(256, 2), dim3(256), 0, stream,
                       P2h, P2l, Bh + 64512, Bl + 64512, b5, A5h, A5l, nullptr);
    // conv6: K=1152, fp16 hi/lo out for MFMA FC1, BK=64
    hipLaunchKernelGGL((k_mgemm<128, 128, 16, false, 64>), dim3(256, 2), dim3(256), 0, stream,
                       A5h, A5l, Bh + 138240, Bl + 138240, b6, A6h, A6l, nullptr);
    // FC1 on MFMA: grid (8 n-blocks, 64 k-chunks)
    hipLaunchKernelGGL(k_fc1m, dim3(8, 64), dim3(256), 0, stream,
                       A6h, A6l, wl1, FP1);
    hipLaunchKernelGGL(k_fc_reduce<64>, dim3(64), dim3(256), 0, stream, FP1, bl1, H1);
    hipLaunchKernelGGL((k_fc_partial<512, 32, 4, false>), dim3(8, 16), dim3(256), 0, stream,
                       H1, wl2, FP2);
    hipLaunchKernelGGL(k_fc_reduce<16>, dim3(64), dim3(256), 0, stream, FP2, bl2, H2);
    hipLaunchKernelGGL(k_final, dim3(128), dim3(256), 0, stream,
                       H2, wl3, bl3, nois, img, out);
}

// Round 15
// 459.933 us; speedup vs baseline: 1.0555x; 1.0255x over previous
//
#include <hip/hip_runtime.h>
#include <math.h>

typedef _Float16 __attribute__((ext_vector_type(8))) half8_t;
typedef _Float16 __attribute__((ext_vector_type(4))) half4_t;
typedef _Float16 __attribute__((ext_vector_type(2))) half2_t;
typedef float    __attribute__((ext_vector_type(4))) float4_t;

// ---------------------------------------------------------------------------
// Kernel 1: fully-MFMA conv1 + conv2 + maxpool4 (block = 16x16 output tile).
// LDS 27.5 KB -> 5 blocks/CU. (R11 structure, best measured.)
// ---------------------------------------------------------------------------
#define POSP 336

__device__ __forceinline__ int c1idx(int slot, int pos) {
    return ((slot * POSP + pos) * 8) ^ (((pos >> 3) & 7) << 3);
}

__global__ __launch_bounds__(256, 5)
void k_conv12(const float* __restrict__ img, const float* __restrict__ b1,
              const _Float16* __restrict__ B1h, const _Float16* __restrict__ B1l,
              const _Float16* __restrict__ B2h, const _Float16* __restrict__ B2l,
              const float* __restrict__ b2,
              _Float16* __restrict__ P1h, _Float16* __restrict__ P1l)
{
    __shared__ float simg[3 * 20 * 25];                    // input halo-2
    __shared__ __align__(16) _Float16 C1h[4 * POSP * 8];   // A, then conv1 out

    const int t  = threadIdx.x;
    const int bt = blockIdx.x;
    const int b  = blockIdx.y;
    const int ty = bt >> 3, tx = bt & 7;
    const int oy = ty * 16, ox = tx * 16;

    // ---- Phase A1: stage fp32 halo (bounds-checked ONCE, zero-padded) ----
    for (int i = t; i < 1500; i += 256) {
        const int ci = i / 500, r = i - ci * 500;
        const int yy = r / 25, xx = r - yy * 25;
        const int gy = oy - 2 + yy, gx = ox - 2 + xx;
        float v = 0.f;
        if ((unsigned)gy < 128u && (unsigned)gx < 128u)
            v = img[((b * 3 + ci) * 128 + gy) * 128 + gx];
        simg[i] = v;
    }
    __syncthreads();

    // ---- Phase A2: im2col simg -> C1h (hi only; compile-time tap offsets) --
    #pragma unroll
    for (int hf = 0; hf < 2; ++hf) {
        const int pos = hf * 256 + t;
        if (pos < POSP) {
            const bool val = pos < 324;
            int sb = 0;
            if (val) {
                const int py = pos / 18, px = pos - py * 18;
                sb = py * 25 + px;
            }
            #pragma unroll
            for (int s = 0; s < 4; ++s) {
                half8_t vh = {0,0,0,0,0,0,0,0};
                if (val) {
                    #pragma unroll
                    for (int j = 0; j < 8; ++j) {
                        const int k = s * 8 + j;
                        if (k < 27) {
                            const int ci = k / 9, tap = k - ci * 9;   // const
                            const int dy = tap / 3, dx = tap - dy * 3; // const
                            vh[j] = (_Float16)simg[sb + (ci * 20 + dy) * 25 + dx];
                        }
                    }
                }
                *(half8_t*)(&C1h[c1idx(s, pos)]) = vh;
            }
        }
    }
    __syncthreads();

    const int wv   = __builtin_amdgcn_readfirstlane(t >> 6);
    const int lane = t & 63;
    const int fr   = lane >> 4;
    const int ml   = lane & 15;

    // ---- Phase B: conv1 MFMA, transposed, 2-term: D[ch][pos] = w @ xh ----
    half8_t wAh[2], wAl[2];
    #pragma unroll
    for (int mt = 0; mt < 2; ++mt) {
        wAh[mt] = *(const half8_t*)(B1h + (mt * 64 + lane) * 8);
        wAl[mt] = *(const half8_t*)(B1l + (mt * 64 + lane) * 8);
    }
    float4_t acc1[6][2];
    #pragma unroll
    for (int q = 0; q < 6; ++q)
        #pragma unroll
        for (int mt = 0; mt < 2; ++mt)
            acc1[q][mt] = (float4_t){0.f, 0.f, 0.f, 0.f};

    #pragma unroll
    for (int q = 0; q < 6; ++q) {
        const int nt = wv + q * 4;
        if (nt < 21) {
            const int ri = c1idx(fr, nt * 16 + ml);
            const half8_t dh = *(const half8_t*)(&C1h[ri]);
            #pragma unroll
            for (int mt = 0; mt < 2; ++mt) {
                acc1[q][mt] = __builtin_amdgcn_mfma_f32_16x16x32_f16(wAh[mt], dh, acc1[q][mt], 0, 0, 0);
                acc1[q][mt] = __builtin_amdgcn_mfma_f32_16x16x32_f16(wAl[mt], dh, acc1[q][mt], 0, 0, 0);
            }
        }
    }
    __syncthreads();          // all A reads done; buffer reusable

    // ---- Phase C: epilogue -> overwrite C1h (hi only). ----
    const float4_t bA = *(const float4_t*)(b1 + fr * 4);
    const float4_t bB = *(const float4_t*)(b1 + 16 + fr * 4);
    #pragma unroll
    for (int q = 0; q < 6; ++q) {
        const int nt = wv + q * 4;
        if (nt < 21) {
            const int pos = nt * 16 + ml;
            if (pos < 324) {
                const int py = pos / 18, px = pos - py * 18;
                const int gy = oy + py - 1, gx = ox + px - 1;
                const bool ok = (unsigned)gy < 128u && (unsigned)gx < 128u;
                #pragma unroll
                for (int mt = 0; mt < 2; ++mt) {
                    const int slot = mt * 2 + (fr >> 1);
                    const int wi = c1idx(slot, pos) + (fr & 1) * 4;
                    const float4_t bb = mt ? bB : bA;
                    half4_t oh;
                    #pragma unroll
                    for (int r = 0; r < 4; ++r) {
                        const float v = ok ? fmaxf(acc1[q][mt][r] + bb[r], 0.f) : 0.f;
                        oh[r] = (_Float16)v;
                    }
                    *(half4_t*)(&C1h[wi]) = oh;
                }
            }
        }
    }
    __syncthreads();

    // ---- Phase D: conv2 implicit-GEMM 2-term, wave wv owns rows wv*4.. ----
    float4_t acc[4][2];
    #pragma unroll
    for (int i = 0; i < 4; ++i)
        #pragma unroll
        for (int nt = 0; nt < 2; ++nt)
            acc[i][nt] = (float4_t){0.f, 0.f, 0.f, 0.f};

    #pragma unroll 1
    for (int tap = 0; tap < 9; ++tap) {
        const int dy = tap / 3, dx = tap - dy * 3;
        half8_t bh[2], bl[2];
        #pragma unroll
        for (int nt = 0; nt < 2; ++nt) {
            const int bo = ((tap * 2 + nt) * 64 + lane) * 8;
            bh[nt] = *(const half8_t*)(B2h + bo);
            bl[nt] = *(const half8_t*)(B2l + bo);
        }
        half8_t ah[4];
        #pragma unroll
        for (int i = 0; i < 4; ++i) {
            const int pos = (wv * 4 + i + dy) * 18 + ml + dx;
            ah[i] = *(const half8_t*)(&C1h[c1idx(fr, pos)]);
        }
        #pragma unroll
        for (int nt = 0; nt < 2; ++nt)
            #pragma unroll
            for (int i = 0; i < 4; ++i)
                acc[i][nt] = __builtin_amdgcn_mfma_f32_16x16x32_f16(ah[i], bh[nt], acc[i][nt], 0, 0, 0);
        #pragma unroll
        for (int nt = 0; nt < 2; ++nt)
            #pragma unroll
            for (int i = 0; i < 4; ++i)
                acc[i][nt] = __builtin_amdgcn_mfma_f32_16x16x32_f16(ah[i], bl[nt], acc[i][nt], 0, 0, 0);
    }

    // ---- maxpool4 (thread-local) + bias + relu + hi/lo store ----
    const int py = ty * 4 + wv;
    const int px = tx * 4 + fr;
    #pragma unroll
    for (int nt = 0; nt < 2; ++nt) {
        float m = -1e30f;
        #pragma unroll
        for (int i = 0; i < 4; ++i)
            #pragma unroll
            for (int r = 0; r < 4; ++r)
                m = fmaxf(m, acc[i][nt][r]);
        const int oc = nt * 16 + ml;
        const float v = fmaxf(m + b2[oc], 0.f);
        const _Float16 h = (_Float16)v;
        const int base = ((b * 32 + py) * 32 + px) * 32 + oc;
        P1h[base] = h;
        P1l[base] = (_Float16)(v - (float)h);
    }
}

// ---------------------------------------------------------------------------
// Weight repack: fp16 hi/lo MFMA-fragment packs for w2..w6 (+ w1, K padded
// 27->32). Frag order: Bh[((c*NT + ntg)*64 + lane)*8 + j], element B[k][n]:
//   n = ntg*16 + (lane&15), k = c*32 + (lane>>4)*8 + j.
// ---------------------------------------------------------------------------
__global__ void k_wrepackm(const float* __restrict__ w1, const float* __restrict__ w2,
                           const float* __restrict__ w3, const float* __restrict__ w4,
                           const float* __restrict__ w5, const float* __restrict__ w6,
                           _Float16* __restrict__ Bh, _Float16* __restrict__ Bl,
                           _Float16* __restrict__ B1h, _Float16* __restrict__ B1l)
{
    int idx = blockIdx.x * 256 + threadIdx.x;
    if (idx >= 285696) {
        const int i = idx - 285696;
        if (i >= 1024) return;
        const int ntg = i >> 9, rr = i & 511;
        const int lane = rr >> 3, j = rr & 7;
        const int k = (lane >> 4) * 8 + j;
        const int n = ntg * 16 + (lane & 15);
        const float v = (k < 27) ? w1[n * 27 + k] : 0.f;
        const _Float16 h = (_Float16)v;
        B1h[i] = h;
        B1l[i] = (_Float16)(v - (float)h);
        return;
    }
    const float* w; int CIN, COUT, off;
    if (idx < 9216)        { w = w2; CIN = 32;  COUT = 32;  off = 0; }
    else if (idx < 27648)  { idx -= 9216;   w = w3; CIN = 32;  COUT = 64;  off = 9216; }
    else if (idx < 64512)  { idx -= 27648;  w = w4; CIN = 64;  COUT = 64;  off = 27648; }
    else if (idx < 138240) { idx -= 64512;  w = w5; CIN = 64;  COUT = 128; off = 64512; }
    else                   { idx -= 138240; w = w6; CIN = 128; COUT = 128; off = 138240; }
    const int NT  = COUT / 16;
    const int c   = idx / (NT * 512);
    const int r   = idx - c * NT * 512;
    const int ntg = r >> 9;
    const int rr  = r & 511;
    const int lane = rr >> 3, j = rr & 7;
    const int k   = c * 32 + (lane >> 4) * 8 + j;
    const int tap = k / CIN, ci = k - tap * CIN;
    const int oc  = ntg * 16 + (lane & 15);
    const float v = w[(oc * CIN + ci) * 9 + tap];
    const _Float16 h = (_Float16)v;
    Bh[off + idx] = h;
    Bl[off + idx] = (_Float16)(v - (float)h);
}

// ---------------------------------------------------------------------------
// MFMA implicit-GEMM conv3x3. BM x BN=64 tile; 4 waves.
// BM=128: wave = 2 m-tiles x 4 n-tiles (conv3/4, grid-matched 4/CU).
// BM=64 (R15): wave = 1 m-tile x 4 n-tiles -> grid DOUBLES for conv5/6
//   (512->1024 blocks = 2->4 blocks/CU; latency-bound regime, occupancy
//   is the proven lever per R10). MFMA order per output unchanged ->
//   bitwise-identical results.
// BK=64 for CIN>=64 (two 32-k chunks per barrier pair). conv3 BK=32.
// Hi/lo dual-plane activations, 3-term split (fp32-class).
// ---------------------------------------------------------------------------
template<int CIN, int COUT, int HW, bool OUTF32, int BK, int BM>
__global__ __launch_bounds__(256, 2)
void k_mgemm(const _Float16* __restrict__ inh, const _Float16* __restrict__ inl,
             const _Float16* __restrict__ Bh, const _Float16* __restrict__ Bl,
             const float* __restrict__ bias,
             _Float16* __restrict__ outh, _Float16* __restrict__ outl,
             float* __restrict__ outf)
{
    constexpr int NCH = CIN * 9 / BK;
    constexpr int SUB = BK / 32;
    constexpr int NT  = COUT / 16;
    constexpr int MT  = BM / 64;          // m-tiles per wave
    constexpr int LOG = (HW == 32) ? 5 : 4;
    constexpr int PS  = BK + ((BK == 64) ? 4 : 8);
    constexpr int NJ  = BM * BK / 2048;   // staging iterations
    constexpr int GPR = BK / 8;           // half8 groups per row
    __shared__ _Float16 Ash[BM * PS];
    __shared__ _Float16 Asl[BM * PS];

    const int t    = threadIdx.x;
    const int wv   = t >> 6;
    const int lane = t & 63;
    const int m0   = blockIdx.x * BM;
    const int nb   = blockIdx.y;

    int sm[NJ], sg[NJ], sb[NJ], sy[NJ], sx[NJ];
    #pragma unroll
    for (int j = 0; j < NJ; ++j) {
        const int q = t + 256 * j;
        sm[j] = q / GPR;
        sg[j] = q - sm[j] * GPR;
        const int m  = m0 + sm[j];
        const int yx = m & (HW * HW - 1);
        sb[j] = m >> (2 * LOG);
        sy[j] = yx >> LOG;
        sx[j] = yx & (HW - 1);
    }

    const int mt0 = wv * MT;
    const int fr  = lane >> 4;
    const int ml  = lane & 15;

    float4_t acc[MT][4];
    #pragma unroll
    for (int mt = 0; mt < MT; ++mt)
        #pragma unroll
        for (int tn = 0; tn < 4; ++tn)
            acc[mt][tn] = (float4_t){0.f, 0.f, 0.f, 0.f};

    #pragma unroll 1
    for (int ch = 0; ch < NCH; ++ch) {
        const int kb  = ch * BK;
        const int tap = kb / CIN;
        const int c0  = kb - tap * CIN;
        const int dy  = tap / 3 - 1, dx = tap - (tap / 3) * 3 - 1;

        if (ch) __syncthreads();
        #pragma unroll
        for (int j = 0; j < NJ; ++j) {
            const int iy = sy[j] + dy, ix = sx[j] + dx;
            half8_t vh = {0, 0, 0, 0, 0, 0, 0, 0};
            half8_t vl = {0, 0, 0, 0, 0, 0, 0, 0};
            if ((unsigned)iy < (unsigned)HW && (unsigned)ix < (unsigned)HW) {
                const int o = ((sb[j] * HW + iy) * HW + ix) * CIN + c0 + sg[j] * 8;
                vh = *(const half8_t*)(inh + o);
                vl = *(const half8_t*)(inl + o);
            }
            *(half8_t*)(&Ash[sm[j] * PS + sg[j] * 8]) = vh;
            *(half8_t*)(&Asl[sm[j] * PS + sg[j] * 8]) = vl;
        }
        __syncthreads();

        #pragma unroll
        for (int ss = 0; ss < SUB; ++ss) {
            half8_t ah[MT], al[MT];
            #pragma unroll
            for (int mt = 0; mt < MT; ++mt) {
                const int mr = (mt0 + mt) * 16 + ml;
                ah[mt] = *(const half8_t*)(&Ash[mr * PS + ss * 32 + fr * 8]);
                al[mt] = *(const half8_t*)(&Asl[mr * PS + ss * 32 + fr * 8]);
            }
            half8_t bh[4], bl[4];
            #pragma unroll
            for (int tn = 0; tn < 4; ++tn) {
                const int bo = (((ch * SUB + ss) * NT + nb * 4 + tn) * 64 + lane) * 8;
                bh[tn] = *(const half8_t*)(Bh + bo);
                bl[tn] = *(const half8_t*)(Bl + bo);
            }
            #pragma unroll
            for (int tn = 0; tn < 4; ++tn)
                #pragma unroll
                for (int mt = 0; mt < MT; ++mt)
                    acc[mt][tn] = __builtin_amdgcn_mfma_f32_16x16x32_f16(ah[mt], bh[tn], acc[mt][tn], 0, 0, 0);
            #pragma unroll
            for (int tn = 0; tn < 4; ++tn)
                #pragma unroll
                for (int mt = 0; mt < MT; ++mt)
                    acc[mt][tn] = __builtin_amdgcn_mfma_f32_16x16x32_f16(al[mt], bh[tn], acc[mt][tn], 0, 0, 0);
            #pragma unroll
            for (int tn = 0; tn < 4; ++tn)
                #pragma unroll
                for (int mt = 0; mt < MT; ++mt)
                    acc[mt][tn] = __builtin_amdgcn_mfma_f32_16x16x32_f16(ah[mt], bl[tn], acc[mt][tn], 0, 0, 0);
            // (al,bl) term dropped: <= 2^-22 relative contribution.
        }
    }

    // epilogue: C/D frag col=lane&15, row=(lane>>4)*4+reg  [guide m89/m91]
    #pragma unroll
    for (int mt = 0; mt < MT; ++mt)
        #pragma unroll
        for (int tn = 0; tn < 4; ++tn) {
            const int oc = nb * 64 + tn * 16 + ml;
            const float bv = bias[oc];
            #pragma unroll
            for (int r = 0; r < 4; ++r) {
                const int m = m0 + (mt0 + mt) * 16 + fr * 4 + r;
                const float v = fmaxf(acc[mt][tn][r] + bv, 0.f);
                const _Float16 h = (_Float16)v;
                outh[m * COUT + oc] = h;
                outl[m * COUT + oc] = (_Float16)(v - (float)h);
            }
        }
}

// ---------------------------------------------------------------------------
// MFMA FC1: H1-partials = A[128 x 32768] @ wl1[32768 x 512], split-K.
// A from fp16 hi/lo A6 planes; W fp32 direct from wl1 (perm folded), hi/lo
// converted in-LDS. 3-term split = fp32-class. Partials fp32.
// ---------------------------------------------------------------------------
__global__ __launch_bounds__(256, 2)
void k_fc1m(const _Float16* __restrict__ A6h, const _Float16* __restrict__ A6l,
            const float* __restrict__ wl1, float* __restrict__ part)
{
    __shared__ __align__(16) _Float16 Ah[128 * 68];
    __shared__ __align__(16) _Float16 Al[128 * 68];
    __shared__ __align__(16) _Float16 Wh[64 * 68];
    __shared__ __align__(16) _Float16 Wl[64 * 68];

    const int t    = threadIdx.x;
    const int wv   = t >> 6;
    const int lane = t & 63;
    const int fr   = lane >> 4;
    const int ml   = lane & 15;
    const int n0   = blockIdx.x * 64;
    const int kc   = blockIdx.y;

    float4_t acc[2][4];
    #pragma unroll
    for (int mt = 0; mt < 2; ++mt)
        #pragma unroll
        for (int tn = 0; tn < 4; ++tn)
            acc[mt][tn] = (float4_t){0.f, 0.f, 0.f, 0.f};

    #pragma unroll 1
    for (int it = 0; it < 8; ++it) {
        const int kb = kc * 512 + it * 64;
        const int yx = kb >> 7;           // 64-k window never crosses yx
        const int c0 = kb & 127;

        if (it) __syncthreads();
        // stage A [128 b][64 k] hi/lo (coalesced 128B runs per b)
        #pragma unroll
        for (int q = 0; q < 4; ++q) {
            const int lin = q * 256 + t;
            const int bb = lin >> 3, g = lin & 7;
            const int src = (bb * 256 + yx) * 128 + c0 + g * 8;
            *(half8_t*)(&Ah[bb * 68 + g * 8]) = *(const half8_t*)(A6h + src);
            *(half8_t*)(&Al[bb * 68 + g * 8]) = *(const half8_t*)(A6l + src);
        }
        // stage W: wl1 row kref=(c0+kk)*256+yx, 64 n fp32 -> hi/lo [n][68]
        {
            const int kk = t >> 2;
            const float* wrow = wl1 + ((c0 + kk) * 256 + yx) * 512 + n0;
            #pragma unroll
            for (int q = 0; q < 4; ++q) {
                const int nq = (t & 3) + q * 4;
                const float4 v = *(const float4*)(wrow + nq * 4);
                #pragma unroll
                for (int e = 0; e < 4; ++e) {
                    const int n = nq * 4 + e;
                    const float w = (&v.x)[e];
                    const _Float16 h = (_Float16)w;
                    Wh[n * 68 + kk] = h;
                    Wl[n * 68 + kk] = (_Float16)(w - (float)h);
                }
            }
        }
        __syncthreads();

        #pragma unroll
        for (int ss = 0; ss < 2; ++ss) {
            half8_t ah[2], al[2];
            #pragma unroll
            for (int mt = 0; mt < 2; ++mt) {
                const int bb = (wv * 2 + mt) * 16 + ml;
                ah[mt] = *(const half8_t*)(&Ah[bb * 68 + ss * 32 + fr * 8]);
                al[mt] = *(const half8_t*)(&Al[bb * 68 + ss * 32 + fr * 8]);
            }
            half8_t bh[4], bl[4];
            #pragma unroll
            for (int tn = 0; tn < 4; ++tn) {
                const int nn = tn * 16 + ml;
                bh[tn] = *(const half8_t*)(&Wh[nn * 68 + ss * 32 + fr * 8]);
                bl[tn] = *(const half8_t*)(&Wl[nn * 68 + ss * 32 + fr * 8]);
            }
            #pragma unroll
            for (int tn = 0; tn < 4; ++tn)
                #pragma unroll
                for (int mt = 0; mt < 2; ++mt)
                    acc[mt][tn] = __builtin_amdgcn_mfma_f32_16x16x32_f16(ah[mt], bh[tn], acc[mt][tn], 0, 0, 0);
            #pragma unroll
            for (int tn = 0; tn < 4; ++tn)
                #pragma unroll
                for (int mt = 0; mt < 2; ++mt)
                    acc[mt][tn] = __builtin_amdgcn_mfma_f32_16x16x32_f16(al[mt], bh[tn], acc[mt][tn], 0, 0, 0);
            #pragma unroll
            for (int tn = 0; tn < 4; ++tn)
                #pragma unroll
                for (int mt = 0; mt < 2; ++mt)
                    acc[mt][tn] = __builtin_amdgcn_mfma_f32_16x16x32_f16(ah[mt], bl[tn], acc[mt][tn], 0, 0, 0);
        }
    }

    // partials (no bias/relu -- reduce applies them)
    const long pb = (long)kc * 65536;
    #pragma unroll
    for (int mt = 0; mt < 2; ++mt)
        #pragma unroll
        for (int tn = 0; tn < 4; ++tn) {
            const int nn = n0 + tn * 16 + ml;
            #pragma unroll
            for (int r = 0; r < 4; ++r) {
                const int m = (wv * 2 + mt) * 16 + fr * 4 + r;
                part[pb + m * 512 + nn] = acc[mt][tn][r];
            }
        }
}

// ---------------------------------------------------------------------------
// 2x2 maxpool on dual fp16 planes, NHWC [128][32][32][64] -> [128][16][16][64]
// ---------------------------------------------------------------------------
__global__ __launch_bounds__(256)
void k_pool2h(const _Float16* __restrict__ inh, const _Float16* __restrict__ inl,
              _Float16* __restrict__ outh, _Float16* __restrict__ outl)
{
    const int g = blockIdx.x * 256 + threadIdx.x;
    const int c4 = g & 15, xo = (g >> 4) & 15, yo = (g >> 8) & 15, b = g >> 12;
    const int base = ((b * 32 + yo * 2) * 32 + xo * 2) * 64 + c4 * 4;
    const int offs[4] = {0, 64, 2048, 2112};
    float mx[4] = {-1e30f, -1e30f, -1e30f, -1e30f};
    #pragma unroll
    for (int cnd = 0; cnd < 4; ++cnd) {
        const half4_t h = *(const half4_t*)(inh + base + offs[cnd]);
        const half4_t l = *(const half4_t*)(inl + base + offs[cnd]);
        #pragma unroll
        for (int e = 0; e < 4; ++e)
            mx[e] = fmaxf(mx[e], (float)h[e] + (float)l[e]);
    }
    half4_t oh, ol;
    #pragma unroll
    for (int e = 0; e < 4; ++e) {
        const _Float16 h = (_Float16)mx[e];
        oh[e] = h;
        ol[e] = (_Float16)(mx[e] - (float)h);
    }
    const int ob = ((b * 16 + yo) * 16 + xo) * 64 + c4 * 4;
    *(half4_t*)(outh + ob) = oh;
    *(half4_t*)(outl + ob) = ol;
}

// ---------------------------------------------------------------------------
// Split-K FC partial (fp32): A[128 x K] @ B[K x 512] -> part[ky][128][512]
// (FC2 only)
// ---------------------------------------------------------------------------
template<int LDA, int KCHUNK, int TN, bool PERM>
__global__ __launch_bounds__(256, 2)
void k_fc_partial(const float* __restrict__ A, const float* __restrict__ Bw,
                  float* __restrict__ part)
{
    constexpr int BN = 16 * TN;
    constexpr int SA = 140;
    constexpr int SB = (BN == 128) ? 140 : 68;
    __shared__ __align__(16) float As[32 * SA];
    __shared__ __align__(16) float Bs[32 * SB];
    const int t  = threadIdx.x;
    const int tm = t >> 4, tn = t & 15;
    const int n0 = blockIdx.x * BN;
    const int k0 = blockIdx.y * KCHUNK;

    float acc[8][TN];
    #pragma unroll
    for (int r = 0; r < 8; ++r)
        #pragma unroll
        for (int c = 0; c < TN; ++c) acc[r][c] = 0.f;

    #pragma unroll 1
    for (int ks = 0; ks < KCHUNK / 32; ++ks) {
        if (ks) __syncthreads();
        const int kb = k0 + ks * 32;
        for (int i = t; i < 4096; i += 256) {
            const int m = i >> 5, kk = i & 31;
            As[kk * SA + m + ((m >> 5) << 2)] = A[m * LDA + kb + kk];
        }
        for (int i = t; i < 32 * BN; i += 256) {
            const int kk = i / BN, n = i - kk * BN;
            const int krow = kb + kk;
            const int kref = PERM ? ((krow & 127) * 256 + (krow >> 7)) : krow;
            Bs[kk * SB + n + ((n >> 5) << 2)] = Bw[kref * 512 + n0 + n];
        }
        __syncthreads();
        #pragma unroll 2
        for (int kk = 0; kk < 32; ++kk) {
            const float* ap = &As[kk * SA + tm * 8 + ((tm >> 2) << 2)];
            const float* bp = &Bs[kk * SB + tn * TN + (((tn * TN) >> 5) << 2)];
            float a[8], bb[TN];
            #pragma unroll
            for (int q = 0; q < 8; q += 4) {
                const float4 v = *(const float4*)(ap + q);
                a[q] = v.x; a[q + 1] = v.y; a[q + 2] = v.z; a[q + 3] = v.w;
            }
            #pragma unroll
            for (int q = 0; q < TN; q += 4) {
                const float4 v = *(const float4*)(bp + q);
                bb[q] = v.x; bb[q + 1] = v.y; bb[q + 2] = v.z; bb[q + 3] = v.w;
            }
            #pragma unroll
            for (int r = 0; r < 8; ++r)
                #pragma unroll
                for (int c = 0; c < TN; ++c)
                    acc[r][c] = fmaf(a[r], bb[c], acc[r][c]);
        }
    }

    const long pb = (long)blockIdx.y * 65536;
    #pragma unroll
    for (int r = 0; r < 8; ++r)
        #pragma unroll
        for (int c = 0; c < TN; ++c)
            part[pb + (tm * 8 + r) * 512 + n0 + tn * TN + c] = acc[r][c];
}

template<int NS>
__global__ __launch_bounds__(256)
void k_fc_reduce(const float* __restrict__ part, const float* __restrict__ bias,
                 float* __restrict__ H)
{
    const int f = (blockIdx.x * 256 + threadIdx.x) * 4;
    const int m = f >> 9, n = f & 511;
    float s0 = 0.f, s1 = 0.f, s2 = 0.f, s3 = 0.f;
    #pragma unroll 4
    for (int q = 0; q < NS; ++q) {
        const float* p = &part[(q * 128 + m) * 512 + n];
        s0 += p[0]; s1 += p[1]; s2 += p[2]; s3 += p[3];
    }
    H[f]     = fmaxf(s0 + bias[n],     0.f);
    H[f + 1] = fmaxf(s1 + bias[n + 1], 0.f);
    H[f + 2] = fmaxf(s2 + bias[n + 2], 0.f);
    H[f + 3] = fmaxf(s3 + bias[n + 3], 0.f);
}

// ---------------------------------------------------------------------------
// Final: FC3 + sampling + patch gather
// ---------------------------------------------------------------------------
__device__ __forceinline__ float softplusf(float x) {
    return (x > 20.f) ? x : log1pf(expf(x));
}
__device__ __forceinline__ float sigmoidf_(float x) {
    return 1.f / (1.f + expf(-x));
}

__global__ __launch_bounds__(256)
void k_final(const float* __restrict__ H2, const float* __restrict__ wl3,
             const float* __restrict__ bl3, const float* __restrict__ noise,
             const float* __restrict__ img, float* __restrict__ outp)
{
    __shared__ float h2[512];
    __shared__ float red[144];
    __shared__ float prep[36];
    __shared__ int ptsh[12], ptsw[12];
    const int b = blockIdx.x, t = threadIdx.x;

    h2[t]       = H2[b * 512 + t];
    h2[t + 256] = H2[b * 512 + 256 + t];
    __syncthreads();

    if (t < 144) {
        const int n = t >> 2, q = t & 3;
        float s = 0.f;
        for (int k = q * 128; k < q * 128 + 128; ++k)
            s = fmaf(h2[k], wl3[k * 36 + n], s);
        red[t] = s;
    }
    __syncthreads();
    if (t < 36)
        prep[t] = red[t * 4] + red[t * 4 + 1] + red[t * 4 + 2] + red[t * 4 + 3] + bl3[t];
    __syncthreads();

    if (t < 12) {
        const float m0 = prep[t * 3], m1 = prep[t * 3 + 1], sv = prep[t * 3 + 2];
        const float sig = softplusf(sv + 2.0f) * 128.f + 1e-7f;
        const float n0 = noise[(b * 12 + t) * 2], n1 = noise[(b * 12 + t) * 2 + 1];
        const float sa0 = m0 + sig * n0;
        const float sa1 = m1 + sig * n1;
        int p0 = (int)rintf(sigmoidf_(sa0) * 111.f);
        int p1 = (int)rintf(sigmoidf_(sa1) * 111.f);
        p0 = min(max(p0, 0), 111);
        p1 = min(max(p1, 0), 111);
        const int RM = 1179648;
        outp[RM        + (b * 12 + t) * 2 + 0] = m0;
        outp[RM        + (b * 12 + t) * 2 + 1] = m1;
        outp[RM + 3072 + (b * 12 + t) * 2 + 0] = sig;
        outp[RM + 3072 + (b * 12 + t) * 2 + 1] = sig;
        outp[RM + 6144 + (b * 12 + t) * 2 + 0] = sa0;
        outp[RM + 6144 + (b * 12 + t) * 2 + 1] = sa1;
        ptsh[t] = p0;
        ptsw[t] = p1;
    }
    __syncthreads();

    for (int i = t; i < 9216; i += 256) {
        const int g  = i / 768, r = i - g * 768;
        const int c  = r >> 8, r2 = r & 255;
        const int y  = r2 >> 4, x = r2 & 15;
        outp[b * 9216 + i] = img[((b * 3 + c) * 128 + ptsh[g] + y) * 128 + (ptsw[g] + x)];
    }
}

// ---------------------------------------------------------------------------
extern "C" void kernel_launch(void* const* d_in, const int* in_sizes, int n_in,
                              void* d_out, int out_size, void* d_ws, size_t ws_size,
                              hipStream_t stream)
{
    const float* img  = (const float*)d_in[0];
    const float* nois = (const float*)d_in[1];
    const float* w1 = (const float*)d_in[2];  const float* b1 = (const float*)d_in[3];
    const float* w2 = (const float*)d_in[4];  const float* b2 = (const float*)d_in[5];
    const float* w3 = (const float*)d_in[6];  const float* b3 = (const float*)d_in[7];
    const float* w4 = (const float*)d_in[8];  const float* b4 = (const float*)d_in[9];
    const float* w5 = (const float*)d_in[10]; const float* b5 = (const float*)d_in[11];
    const float* w6 = (const float*)d_in[12]; const float* b6 = (const float*)d_in[13];
    const float* wl1 = (const float*)d_in[14]; const float* bl1 = (const float*)d_in[15];
    const float* wl2 = (const float*)d_in[16]; const float* bl2 = (const float*)d_in[17];
    const float* wl3 = (const float*)d_in[18]; const float* bl3 = (const float*)d_in[19];
    float* out = (float*)d_out;
    float* ws  = (float*)d_ws;

    // workspace (float units). Activation regions span [0 .. 20971520).
    _Float16* P1h = (_Float16*)(ws);               // [128*32*32*32] halves
    _Float16* P1l = (_Float16*)(ws + 2097152);
    _Float16* A3h = (_Float16*)(ws + 4194304);     // [128*32*32*64]
    _Float16* A3l = (_Float16*)(ws + 8388608);
    _Float16* A4h = (_Float16*)(ws + 12582912);    // [128*32*32*64]
    _Float16* A4l = (_Float16*)(ws + 16777216);    // ..20971520
    _Float16* P2h = (_Float16*)(ws);               // [128*16*16*64] (P1 dead)
    _Float16* P2l = (_Float16*)(ws + 1048576);
    _Float16* A5h = (_Float16*)(ws + 4194304);     // [128*16*16*128] (A3 dead)
    _Float16* A5l = (_Float16*)(ws + 6291456);
    _Float16* A6h = (_Float16*)(ws + 8388608);     // [32768*128] halves
    _Float16* A6l = (_Float16*)(ws + 10485760);
    float* FP1 = ws + 12582912;                    // [64][128][512] (A4h dead)
    float* H1  = ws + 16777216;                    // [128][512]     (A4l dead)
    float* FP2 = ws + 16842752;                    // [16][128][512]
    float* H2  = ws + 17891328;                    // [128][512]
    _Float16* B1h = (_Float16*)(ws + 17956864);    // 1024 halves (w1 pack)
    _Float16* B1l = (_Float16*)(ws + 17957376);
    _Float16* Bh = (_Float16*)(ws + 20971520);     // 285696 halves (w2..w6)
    _Float16* Bl = (_Float16*)(ws + 21114368);     // ends 21257216 fl = 85 MB

    hipLaunchKernelGGL(k_wrepackm, dim3(1120), dim3(256), 0, stream,
                       w1, w2, w3, w4, w5, w6, Bh, Bl, B1h, B1l);

    // conv1+conv2+pool4: grid = 8x8 tiles x 128 batch
    hipLaunchKernelGGL(k_conv12, dim3(64, 128), dim3(256), 0, stream,
                       img, b1, B1h, B1l, Bh + 0, Bl + 0, b2, P1h, P1l);
    // conv3: M=131072, K=288, COUT=64 (CIN=32 -> BK=32), BM=128
    hipLaunchKernelGGL((k_mgemm<32, 64, 32, false, 32, 128>), dim3(1024, 1), dim3(256), 0, stream,
                       P1h, P1l, Bh + 9216, Bl + 9216, b3, A3h, A3l, nullptr);
    // conv4: K=576, BK=64, BM=128
    hipLaunchKernelGGL((k_mgemm<64, 64, 32, false, 64, 128>), dim3(1024, 1), dim3(256), 0, stream,
                       A3h, A3l, Bh + 27648, Bl + 27648, b4, A4h, A4l, nullptr);
    hipLaunchKernelGGL(k_pool2h, dim3(2048), dim3(256), 0, stream, A4h, A4l, P2h, P2l);
    // conv5: M=32768, K=576, COUT=128, BK=64, BM=64 (R15: 2->4 blocks/CU)
    hipLaunchKernelGGL((k_mgemm<64, 128, 16, false, 64, 64>), dim3(512, 2), dim3(256), 0, stream,
                       P2h, P2l, Bh + 64512, Bl + 64512, b5, A5h, A5l, nullptr);
    // conv6: K=1152, fp16 hi/lo out for MFMA FC1, BK=64, BM=64 (R15)
    hipLaunchKernelGGL((k_mgemm<128, 128, 16, false, 64, 64>), dim3(512, 2), dim3(256), 0, stream,
                       A5h, A5l, Bh + 138240, Bl + 138240, b6, A6h, A6l, nullptr);
    // FC1 on MFMA: grid (8 n-blocks, 64 k-chunks)
    hipLaunchKernelGGL(k_fc1m, dim3(8, 64), dim3(256), 0, stream,
                       A6h, A6l, wl1, FP1);
    hipLaunchKernelGGL(k_fc_reduce<64>, dim3(64), dim3(256), 0, stream, FP1, bl1, H1);
    hipLaunchKernelGGL((k_fc_partial<512, 32, 4, false>), dim3(8, 16), dim3(256), 0, stream,
                       H1, wl2, FP2);
    hipLaunchKernelGGL(k_fc_reduce<16>, dim3(64), dim3(256), 0, stream, FP2, bl2, H2);
    hipLaunchKernelGGL(k_final, dim3(128), dim3(256), 0, stream,
                       H2, wl3, bl3, nois, img, out);
}